// Round 20
// baseline (418.635 us; speedup 1.0000x reference)
//
#include <hip/hip_runtime.h>
#include <math.h>

namespace {
constexpr int kB = 16, kV = 30, kNV = 1501, kNE = 2001, kH = 128, kD = 128,
              kL = 2, kOut = 25, kNT = 100000, kE = 800000, kM = kB * kV;
constexpr int kNB = (kNT + 255) / 256;  // 391 scan blocks
constexpr int kKT = 47;                 // k-chunks of 32 (47*32 = 1504 >= 1501)
constexpr int kKP = kKT * 32;           // padded K = 1504
constexpr int kKSZ = 8;                 // split-K blocks for z
constexpr int kKCH = 6;                 // k-chunks per split slice (8*6=48 >= 47)
constexpr int kNVZ = 1536;              // padded n-stride for z partials
constexpr int kMZ = 512;                // padded M = 16 b x 32 v
}

// PN[n] = node_emb[n]@lin_w^T + lin_b; PQ2[n] = relu(PN[n])@W1^T,
// PQ2[kNV+n] = relu(-PN[n])@W1^T; PS[n] = PN[n]@W1^T + b1.
__global__ void pn_kernel(const float* __restrict__ emb, const float* __restrict__ lw,
                          const float* __restrict__ lb, const float* __restrict__ cw,
                          const float* __restrict__ cb, float* __restrict__ pn,
                          float* __restrict__ pq2, float* __restrict__ ps) {
  int n = blockIdx.x, h = threadIdx.x;
  __shared__ float erow[kD];
  __shared__ float row[kD];
  erow[h] = emb[(size_t)n * kD + h];
  __syncthreads();
  float acc = lb[h];
#pragma unroll 8
  for (int d = 0; d < kD; d++) acc += erow[d] * lw[h * kD + d];
  pn[(size_t)n * kH + h] = acc;
  row[h] = acc;
  __syncthreads();
  float ap = 0.f, am = 0.f, aps = cb[h];
  const float* wr = cw + h * kD;
#pragma unroll 8
  for (int d = 0; d < kD; d++) {
    float r = row[d];
    float w = wr[d];
    ap = fmaf(fmaxf(r, 0.f), w, ap);
    am = fmaf(fmaxf(-r, 0.f), w, am);
    aps = fmaf(r, w, aps);
  }
  pq2[(size_t)n * kH + h] = ap;
  pq2[(size_t)(kNV + n) * kH + h] = am;
  ps[(size_t)n * kH + h] = aps;
}

// node branch partials
__global__ void xnode_kernel(const int* __restrict__ ehr, const float* __restrict__ pn,
                             float* __restrict__ xacc, int* __restrict__ cnte) {
  int b = blockIdx.x;
  int c = blockIdx.y;
  int h = threadIdx.x;
  int n0 = c * 128;
  __shared__ int flags[128];
  int gn = n0 + h;
  flags[h] = (gn < kNV) ? ehr[(size_t)b * kNV + gn] : 0;
  __syncthreads();
  float acc = 0.f;
  int cnt = 0;
  int n1 = min(n0 + 128, kNV);
  for (int n = n0; n < n1; ++n) {
    if (flags[n - n0]) {
      acc += pn[(size_t)n * kH + h];
      cnt++;
    }
  }
  atomicAdd(&xacc[b * kH + h], acc);
  if (h == 0) atomicAdd(&cnte[b], cnt);
}

// u[l][d] = sum_h wr_w[l][h]*lin_w[h][d] ; c[l] = wr_w[l].lin_b + wr_b[l]
__global__ void uc_kernel(const float* __restrict__ wrw, const float* __restrict__ wrb,
                          const float* __restrict__ lw, const float* __restrict__ lb,
                          float* __restrict__ uc) {
  int t = threadIdx.x;
  int l = t >> 7, d = t & 127;
  float s = 0.f;
  for (int h = 0; h < kH; h++) s += wrw[l * kH + h] * lw[h * kD + d];
  uc[t] = s;
  if (t < kL) {
    float c = wrb[t];
    for (int h = 0; h < kH; h++) c += wrw[t * kH + h] * lb[h];
    uc[256 + t] = c;
  }
}

// wrel[l][r] = sigmoid(edge_emb[r] . u[l] + c[l])
__global__ void wrel_kernel(const float* __restrict__ eemb, const float* __restrict__ uc,
                            float* __restrict__ wrel) {
  int idx = blockIdx.x * blockDim.x + threadIdx.x;
  if (idx >= kL * kNE) return;
  int l = idx / kNE, r = idx % kNE;
  float z = uc[256 + l];
  const float* u = uc + l * 128;
  const float* er = eemb + (size_t)r * kD;
  for (int d = 0; d < kD; d++) z += er[d] * u[d];
  wrel[idx] = 1.f / (1.f + expf(-z));
}

// beta[l][b*V+v] = tanh(vn[b,v,:].beta_w[l] + beta_b[l]) * exp(0.01*(V-v))
__global__ void beta_kernel(const int* __restrict__ vn, const float* __restrict__ bw,
                            const float* __restrict__ bb, float* __restrict__ beta) {
  int blk = blockIdx.x;
  int l = blk / kM, r = blk % kM;
  int v = r % kV;
  int lane = threadIdx.x;
  const int* row = vn + (size_t)r * kNV;
  const float* w = bw + (size_t)l * kNV;
  float s = 0.f;
  for (int k = lane; k < kNV; k += 64) s += (float)row[k] * w[k];
  for (int off = 32; off > 0; off >>= 1) s += __shfl_down(s, off, 64);
  if (lane == 0) {
    float lam = expf(0.01f * (float)(kV - v));
    beta[blk] = tanhf(s + bb[l]) * lam;
  }
}

// VNTALL[k][m] = (float)vn[b][v][k], m = b*32+v (512 cols), k padded to 1504.
__global__ void vnt_kernel(const int* __restrict__ vn, float* __restrict__ vnt) {
  int b = blockIdx.x, kt = blockIdx.y;
  int k0 = kt * 32;
  int tid = threadIdx.x;  // 256
  __shared__ float t[32][33];  // t[v][kk]
#pragma unroll
  for (int i = 0; i < 4; ++i) {
    int e = tid + i * 256;  // 1024 = 32v x 32k
    int v = e >> 5, kk = e & 31;
    int gk = k0 + kk;
    t[v][kk] = (v < kV && gk < kNV) ? (float)vn[(size_t)(b * kV + v) * kNV + gk] : 0.f;
  }
  __syncthreads();
  float* out = vnt + (size_t)k0 * kMZ + b * 32;
#pragma unroll
  for (int i = 0; i < 4; ++i) {
    int e = tid + i * 256;
    int kk = e >> 5, v = e & 31;
    out[(size_t)kk * kMZ + v] = t[v][kk];
  }
}

// Split-K partial z, full-M GEMM: zp[ks][l][m][n] = sum_{k in slice} VNTALL[k][m]*aw[l][n][k]
// 64m x 128n tile, 4x8 per thread, grid (12, 8, kL*kKSZ=16) = 1536 blocks.
__global__ void zpart_kernel(const float* __restrict__ vntall, const float* __restrict__ aw,
                             float* __restrict__ zp) {
  const int zidx = blockIdx.z;
  const int l = zidx / kKSZ, ks = zidx % kKSZ;
  const int mb = blockIdx.y * 64;
  const int nb = blockIdx.x * 128;
  const int tid = threadIdx.x;  // 256
  __shared__ float As[32 * 64];   // 8 KB [kk][m], k-major (no transpose needed)
  __shared__ float Bs[32 * 128];  // 16 KB [kk][n], XOR granule-swizzled
  const float* awl = aw + (size_t)l * kNV * kNV;
  const int tx = tid & 15;   // n pair-granule: cols tx*4 and 64+tx*4
  const int ty = tid >> 4;   // m granule: rows ty*4
  const int snn = tid >> 3;  // Bs staging n within 32-row group
  const int sk4 = (tid & 7) * 4;
  const int ct0 = ks * kKCH;
  const int ct1 = min(ct0 + kKCH, kKT);
  float acc[4][8] = {};
  for (int kt = ct0; kt < ct1; ++kt) {
    const int k0 = kt * 32;
    __syncthreads();
    // ---- stage As: 32k x 64m, plain float4 copies (both k-major) ----
#pragma unroll
    for (int i = 0; i < 2; ++i) {
      int e = tid + i * 256;  // 512 float4
      int kk = e >> 4, mq = (e & 15) * 4;
      *(float4*)&As[kk * 64 + mq] =
          *(const float4*)(vntall + (size_t)(k0 + kk) * kMZ + mb + mq);
    }
    // ---- stage Bs: 128n x 32k with XOR granule swizzle ----
    if (k0 + 32 <= kNV) {
#pragma unroll
      for (int i = 0; i < 4; ++i) {
        int nn = snn + 32 * i;
        int gn = nb + nn;
        float4 a = (gn < kNV) ? *(const float4*)(awl + (size_t)gn * kNV + k0 + sk4)
                              : float4{0.f, 0.f, 0.f, 0.f};
        float av[4] = {a.x, a.y, a.z, a.w};
#pragma unroll
        for (int j = 0; j < 4; ++j) {
          int kk = sk4 + j;
          int g = (nn >> 2) ^ (kk >> 2);
          Bs[kk * 128 + (g << 2) + (nn & 3)] = av[j];
        }
      }
    } else {
#pragma unroll
      for (int i = 0; i < 4; ++i) {
        int nn = snn + 32 * i;
        int gn = nb + nn;
#pragma unroll
        for (int j = 0; j < 4; ++j) {
          int kk = sk4 + j;
          int gk = k0 + kk;
          float v = (gn < kNV && gk < kNV) ? awl[(size_t)gn * kNV + gk] : 0.f;
          int g = (nn >> 2) ^ (kk >> 2);
          Bs[kk * 128 + (g << 2) + (nn & 3)] = v;
        }
      }
    }
    __syncthreads();
#pragma unroll 4
    for (int kk = 0; kk < 32; ++kk) {
      float4 a4 = *(const float4*)&As[kk * 64 + ty * 4];
      float4 b0 = *(const float4*)&Bs[kk * 128 + ((tx ^ (kk >> 2)) << 2)];
      float4 b1 = *(const float4*)&Bs[kk * 128 + (((tx + 16) ^ (kk >> 2)) << 2)];
      float am[4] = {a4.x, a4.y, a4.z, a4.w};
      float bn[8] = {b0.x, b0.y, b0.z, b0.w, b1.x, b1.y, b1.z, b1.w};
#pragma unroll
      for (int i2 = 0; i2 < 4; ++i2)
#pragma unroll
        for (int j2 = 0; j2 < 8; ++j2) acc[i2][j2] += am[i2] * bn[j2];
    }
  }
  float* zb = zp + (size_t)(ks * kL + l) * kMZ * kNVZ;
#pragma unroll
  for (int i2 = 0; i2 < 4; ++i2) {
    int m = mb + ty * 4 + i2;
    *(float4*)&zb[(size_t)m * kNVZ + nb + tx * 4] =
        float4{acc[i2][0], acc[i2][1], acc[i2][2], acc[i2][3]};
    *(float4*)&zb[(size_t)m * kNVZ + nb + 64 + tx * 4] =
        float4{acc[i2][4], acc[i2][5], acc[i2][6], acc[i2][7]};
  }
}

// attn[l][b][n] = sum_v softmax_v(sum_ks zp) * beta[l][b][v]
__global__ void zsm_kernel(const float* __restrict__ zp, const float* __restrict__ beta,
                           float* __restrict__ attn) {
  int idx = blockIdx.x * blockDim.x + threadIdx.x;
  if (idx >= kL * kB * kNV) return;
  int n = idx % kNV;
  int lb_ = idx / kNV;  // l*kB + b
  int l = lb_ / kB, b = lb_ % kB;
  const size_t PSTR = (size_t)kL * kMZ * kNVZ;  // partial stride
  const float* p = zp + ((size_t)l * kMZ + b * 32) * kNVZ + n;
  float zz[kV];
  float m = -1e30f;
#pragma unroll
  for (int v = 0; v < kV; ++v) {
    size_t o = (size_t)v * kNVZ;
    float s = 0.f;
#pragma unroll
    for (int q = 0; q < kKSZ; ++q) s += p[o + (size_t)q * PSTR];
    zz[v] = s;
    m = fmaxf(m, s);
  }
  float s = 0.f, num = 0.f;
  const float* bet = beta + lb_ * kV;
#pragma unroll
  for (int v = 0; v < kV; ++v) {
    float e = expf(zz[v] - m);
    s += e;
    num += e * bet[v];
  }
  attn[idx] = num / s;
}

// ---- CSR build ----
__global__ void hist_kernel(const int* __restrict__ ei, const int* __restrict__ nid,
                            const int* __restrict__ batch, const float* __restrict__ attn,
                            int* __restrict__ deg, int* __restrict__ deg2) {
  int e = blockIdx.x * blockDim.x + threadIdx.x;
  if (e >= kE) return;
  int d = ei[kE + e];
  atomicAdd(&deg[d], 1);
  int s = ei[e];
  float a1 = attn[(size_t)kB * kNV + batch[s] * kNV + nid[s]];
  if (a1 > 0.f) atomicAdd(&deg2[d], 1);
}

__global__ void scan1_kernel(const int* __restrict__ deg, int* __restrict__ off,
                             int* __restrict__ part) {
  int t = threadIdx.x, i = blockIdx.x * 256 + t;
  int v = (i < kNT) ? deg[i] : 0;
  __shared__ int sm[256];
  sm[t] = v;
  __syncthreads();
  for (int o = 1; o < 256; o <<= 1) {
    int x = (t >= o) ? sm[t - o] : 0;
    __syncthreads();
    sm[t] += x;
    __syncthreads();
  }
  if (i < kNT) off[i] = sm[t] - v;
  if (t == 255) part[blockIdx.x] = sm[255];
}

__global__ void scan2_kernel(int* __restrict__ part) {
  int t = threadIdx.x;  // 512
  int v = (t < kNB) ? part[t] : 0;
  __shared__ int sm[512];
  sm[t] = v;
  __syncthreads();
  for (int o = 1; o < 512; o <<= 1) {
    int x = (t >= o) ? sm[t - o] : 0;
    __syncthreads();
    sm[t] += x;
    __syncthreads();
  }
  if (t < kNB) part[t] = sm[t] - v;
}

__global__ void scan3_kernel(int* __restrict__ off, const int* __restrict__ part,
                             int* __restrict__ cursor) {
  int i = blockIdx.x * 256 + threadIdx.x;
  if (i >= kNT) return;
  int o = off[i] + part[blockIdx.x];
  off[i] = o;
  cursor[i] = o;
}

// counts per batch segment: per-block LDS histogram, 16 global atomics/block
__global__ void cnt_kernel(const int* __restrict__ batch, int* __restrict__ cnt) {
  __shared__ int hist[kB];
  int t = threadIdx.x;
  if (t < kB) hist[t] = 0;
  __syncthreads();
  int i = blockIdx.x * blockDim.x + t;
  if (i < kNT) atomicAdd(&hist[batch[i]], 1);
  __syncthreads();
  if (t < kB && hist[t]) atomicAdd(&cnt[t], hist[t]);
}

// scatter: layer-1 CSR (csn sign-folded row, |cs0|w0) + compacted positive CSR
__global__ void scatter_kernel(const int* __restrict__ ei, const int* __restrict__ nid,
                               const int* __restrict__ eid, const int* __restrict__ batch,
                               const float* __restrict__ attn, const float* __restrict__ wrel,
                               int* __restrict__ cursor, int* __restrict__ csn,
                               float* __restrict__ cs0, int* __restrict__ cursor2,
                               int* __restrict__ csrc2, float* __restrict__ cs1c) {
  int e = blockIdx.x * blockDim.x + threadIdx.x;
  if (e >= kE) return;
  int s = ei[e], d = ei[kE + e];
  int b = batch[s], n = nid[s], r = eid[e];
  float a0 = attn[(size_t)b * kNV + n];
  float a1 = attn[(size_t)kB * kNV + b * kNV + n];
  float w0 = wrel[r], w1 = wrel[kNE + r];
  int pos = atomicAdd(&cursor[d], 1);
  csn[pos] = n + ((a0 > 0.f) ? 0 : kNV);
  cs0[pos] = fabsf(a0) * w0;
  if (a1 > 0.f) {
    int p2 = atomicAdd(&cursor2[d], 1);
    csrc2[p2] = s;
    cs1c[p2] = a1 * w1;
  }
}

#define GACC(A, V, C)                                  \
  A.x = fmaf(V.x, C, A.x); A.y = fmaf(V.y, C, A.y);    \
  A.z = fmaf(V.z, C, A.z); A.w = fmaf(V.w, C, A.w);

// Layer 1 in OUTPUT space: xa[node] = relu(PS[nid[node]] + sum_e cs0*PQ2[csn]).
__global__ void l1_kernel(const float* __restrict__ pq2, const float* __restrict__ psTab,
                          const int* __restrict__ nid, const int* __restrict__ csn,
                          const float* __restrict__ cs0, const int* __restrict__ off,
                          const int* __restrict__ endv, float* __restrict__ xa) {
  const int tid = threadIdx.x;  // 512
  const int lane = tid & 63;
  const int sub = lane >> 5, sl = lane & 31;
  const int hw = (tid >> 6) * 2 + sub;  // half-wave 0..15
  int node = blockIdx.x * 16 + hw;
  if (node >= kNT) return;
  const float4* x4 = (const float4*)pq2;
  float4 a0 = ((const float4*)psTab)[(size_t)nid[node] * 32 + sl];
  float4 a1 = {0.f, 0.f, 0.f, 0.f};
  float4 a2 = {0.f, 0.f, 0.f, 0.f};
  float4 a3 = {0.f, 0.f, 0.f, 0.f};
  int j0 = off[node], j1 = endv[node];
  for (int base = j0; base < j1; base += 32) {
    int n = j1 - base;
    if (n > 32) n = 32;
    int sidx = 0;
    float ssc = 0.f;
    if (sl < n) {
      sidx = csn[base + sl];
      ssc = cs0[base + sl];
    }
    int t = 0;
    for (; t + 8 <= n; t += 8) {
      int s0 = __shfl(sidx, sub * 32 + t + 0, 64);
      int s1 = __shfl(sidx, sub * 32 + t + 1, 64);
      int s2 = __shfl(sidx, sub * 32 + t + 2, 64);
      int s3 = __shfl(sidx, sub * 32 + t + 3, 64);
      int s4i = __shfl(sidx, sub * 32 + t + 4, 64);
      int s5 = __shfl(sidx, sub * 32 + t + 5, 64);
      int s6 = __shfl(sidx, sub * 32 + t + 6, 64);
      int s7 = __shfl(sidx, sub * 32 + t + 7, 64);
      float c0 = __shfl(ssc, sub * 32 + t + 0, 64);
      float c1 = __shfl(ssc, sub * 32 + t + 1, 64);
      float c2 = __shfl(ssc, sub * 32 + t + 2, 64);
      float c3 = __shfl(ssc, sub * 32 + t + 3, 64);
      float c4 = __shfl(ssc, sub * 32 + t + 4, 64);
      float c5 = __shfl(ssc, sub * 32 + t + 5, 64);
      float c6 = __shfl(ssc, sub * 32 + t + 6, 64);
      float c7 = __shfl(ssc, sub * 32 + t + 7, 64);
      float4 v0 = x4[(size_t)s0 * 32 + sl];
      float4 v1 = x4[(size_t)s1 * 32 + sl];
      float4 v2 = x4[(size_t)s2 * 32 + sl];
      float4 v3 = x4[(size_t)s3 * 32 + sl];
      float4 v4 = x4[(size_t)s4i * 32 + sl];
      float4 v5 = x4[(size_t)s5 * 32 + sl];
      float4 v6 = x4[(size_t)s6 * 32 + sl];
      float4 v7 = x4[(size_t)s7 * 32 + sl];
      GACC(a0, v0, c0);
      GACC(a1, v1, c1);
      GACC(a2, v2, c2);
      GACC(a3, v3, c3);
      GACC(a0, v4, c4);
      GACC(a1, v5, c5);
      GACC(a2, v6, c6);
      GACC(a3, v7, c7);
    }
    for (; t + 4 <= n; t += 4) {
      int s0 = __shfl(sidx, sub * 32 + t + 0, 64);
      int s1 = __shfl(sidx, sub * 32 + t + 1, 64);
      int s2 = __shfl(sidx, sub * 32 + t + 2, 64);
      int s3 = __shfl(sidx, sub * 32 + t + 3, 64);
      float c0 = __shfl(ssc, sub * 32 + t + 0, 64);
      float c1 = __shfl(ssc, sub * 32 + t + 1, 64);
      float c2 = __shfl(ssc, sub * 32 + t + 2, 64);
      float c3 = __shfl(ssc, sub * 32 + t + 3, 64);
      float4 v0 = x4[(size_t)s0 * 32 + sl];
      float4 v1 = x4[(size_t)s1 * 32 + sl];
      float4 v2 = x4[(size_t)s2 * 32 + sl];
      float4 v3 = x4[(size_t)s3 * 32 + sl];
      GACC(a0, v0, c0);
      GACC(a1, v1, c1);
      GACC(a2, v2, c2);
      GACC(a3, v3, c3);
    }
    for (; t < n; ++t) {
      int s = __shfl(sidx, sub * 32 + t, 64);
      float sc = __shfl(ssc, sub * 32 + t, 64);
      float4 xv = x4[(size_t)s * 32 + sl];
      GACC(a0, xv, sc);
    }
  }
  float4 o;
  o.x = fmaxf(a0.x + a1.x + a2.x + a3.x, 0.f);
  o.y = fmaxf(a0.y + a1.y + a2.y + a3.y, 0.f);
  o.z = fmaxf(a0.z + a1.z + a2.z + a3.z, 0.f);
  o.w = fmaxf(a0.w + a1.w + a2.w + a3.w, 0.f);
  ((float4*)xa)[(size_t)node * 32 + sl] = o;
}

// Fused gather+conv for layer 2 (pool path), 512 threads/block, pure-fma edges.
template <int POOL>
__global__ void gconv_kernel(const float* __restrict__ srcTab,
                             const float* __restrict__ selfTab,
                             const int* __restrict__ cidx, const float* __restrict__ cscal,
                             const int* __restrict__ off, const int* __restrict__ endv,
                             const int* __restrict__ selfIdx, const float* __restrict__ w,
                             const float* __restrict__ bias, float* __restrict__ xout,
                             float* __restrict__ xg, const int* __restrict__ batch) {
  const int nb = blockIdx.x * 64;
  const int tid = threadIdx.x;  // 512
  __shared__ float As[128 * 64];
  __shared__ float Ws[32 * 132];
  const int wv = tid >> 6;
  const int lane = tid & 63;
  const int sub = lane >> 5, sl = lane & 31;
  const int hw = wv * 2 + sub;
  const float4* x4 = (const float4*)srcTab;
  const float4* s4 = (const float4*)selfTab;
  for (int p = 0; p < 4; ++p) {
    int nl = p * 16 + hw;
    int node = nb + nl;
    if (node < kNT) {
      int selfRow = selfIdx ? selfIdx[node] : node;
      float4 a0 = s4[(size_t)selfRow * 32 + sl];
      float4 a1 = {0.f, 0.f, 0.f, 0.f};
      float4 a2 = {0.f, 0.f, 0.f, 0.f};
      float4 a3 = {0.f, 0.f, 0.f, 0.f};
      int j0 = off[node], j1 = endv[node];
      for (int base = j0; base < j1; base += 32) {
        int n = j1 - base;
        if (n > 32) n = 32;
        int sidx = 0;
        float ssc = 0.f;
        if (sl < n) {
          sidx = cidx[base + sl];
          ssc = cscal[base + sl];
        }
        int t = 0;
        for (; t + 8 <= n; t += 8) {
          int s0 = __shfl(sidx, sub * 32 + t + 0, 64);
          int s1 = __shfl(sidx, sub * 32 + t + 1, 64);
          int s2 = __shfl(sidx, sub * 32 + t + 2, 64);
          int s3 = __shfl(sidx, sub * 32 + t + 3, 64);
          int s4i = __shfl(sidx, sub * 32 + t + 4, 64);
          int s5 = __shfl(sidx, sub * 32 + t + 5, 64);
          int s6 = __shfl(sidx, sub * 32 + t + 6, 64);
          int s7 = __shfl(sidx, sub * 32 + t + 7, 64);
          float c0 = __shfl(ssc, sub * 32 + t + 0, 64);
          float c1 = __shfl(ssc, sub * 32 + t + 1, 64);
          float c2 = __shfl(ssc, sub * 32 + t + 2, 64);
          float c3 = __shfl(ssc, sub * 32 + t + 3, 64);
          float c4 = __shfl(ssc, sub * 32 + t + 4, 64);
          float c5 = __shfl(ssc, sub * 32 + t + 5, 64);
          float c6 = __shfl(ssc, sub * 32 + t + 6, 64);
          float c7 = __shfl(ssc, sub * 32 + t + 7, 64);
          float4 v0 = x4[(size_t)s0 * 32 + sl];
          float4 v1 = x4[(size_t)s1 * 32 + sl];
          float4 v2 = x4[(size_t)s2 * 32 + sl];
          float4 v3 = x4[(size_t)s3 * 32 + sl];
          float4 v4 = x4[(size_t)s4i * 32 + sl];
          float4 v5 = x4[(size_t)s5 * 32 + sl];
          float4 v6 = x4[(size_t)s6 * 32 + sl];
          float4 v7 = x4[(size_t)s7 * 32 + sl];
          GACC(a0, v0, c0);
          GACC(a1, v1, c1);
          GACC(a2, v2, c2);
          GACC(a3, v3, c3);
          GACC(a0, v4, c4);
          GACC(a1, v5, c5);
          GACC(a2, v6, c6);
          GACC(a3, v7, c7);
        }
        for (; t + 4 <= n; t += 4) {
          int s0 = __shfl(sidx, sub * 32 + t + 0, 64);
          int s1 = __shfl(sidx, sub * 32 + t + 1, 64);
          int s2 = __shfl(sidx, sub * 32 + t + 2, 64);
          int s3 = __shfl(sidx, sub * 32 + t + 3, 64);
          float c0 = __shfl(ssc, sub * 32 + t + 0, 64);
          float c1 = __shfl(ssc, sub * 32 + t + 1, 64);
          float c2 = __shfl(ssc, sub * 32 + t + 2, 64);
          float c3 = __shfl(ssc, sub * 32 + t + 3, 64);
          float4 v0 = x4[(size_t)s0 * 32 + sl];
          float4 v1 = x4[(size_t)s1 * 32 + sl];
          float4 v2 = x4[(size_t)s2 * 32 + sl];
          float4 v3 = x4[(size_t)s3 * 32 + sl];
          GACC(a0, v0, c0);
          GACC(a1, v1, c1);
          GACC(a2, v2, c2);
          GACC(a3, v3, c3);
        }
        for (; t < n; ++t) {
          int s = __shfl(sidx, sub * 32 + t, 64);
          float sc = __shfl(ssc, sub * 32 + t, 64);
          float4 xv = x4[(size_t)s * 32 + sl];
          GACC(a0, xv, sc);
        }
      }
      float av[4] = {a0.x + a1.x + a2.x + a3.x, a0.y + a1.y + a2.y + a3.y,
                     a0.z + a1.z + a2.z + a3.z, a0.w + a1.w + a2.w + a3.w};
#pragma unroll
      for (int j = 0; j < 4; ++j) {
        int d = sl * 4 + j;
        int g = (nl >> 2) ^ (sl & 15);
        As[d * 64 + (g << 2) + (nl & 3)] = av[j];
      }
    }
  }
  __syncthreads();
  const int tx = tid & 31, ty = tid >> 5;
  const int n0 = tx * 4;
  float acc[4][4] = {};
  for (int kc = 0; kc < 4; ++kc) {
    if (kc) __syncthreads();
#pragma unroll
    for (int i = 0; i < 2; ++i) {
      int fi = tid + i * 512;
      int hh = fi >> 3, c4 = (fi & 7) * 4;
      float4 v = *(const float4*)(w + (size_t)hh * kD + kc * 32 + c4);
      Ws[(c4 + 0) * 132 + hh] = v.x;
      Ws[(c4 + 1) * 132 + hh] = v.y;
      Ws[(c4 + 2) * 132 + hh] = v.z;
      Ws[(c4 + 3) * 132 + hh] = v.w;
    }
    __syncthreads();
#pragma unroll
    for (int dd = 0; dd < 32; ++dd) {
      int d = kc * 32 + dd;
      float4 a = *(const float4*)&As[d * 64 + ((ty ^ ((d >> 2) & 15)) << 2)];
      float4 b0 = *(const float4*)&Ws[dd * 132 + n0];
      float am[4] = {a.x, a.y, a.z, a.w};
      float bn[4] = {b0.x, b0.y, b0.z, b0.w};
#pragma unroll
      for (int i2 = 0; i2 < 4; ++i2)
#pragma unroll
        for (int j2 = 0; j2 < 4; ++j2) acc[i2][j2] += am[i2] * bn[j2];
    }
  }
  float4 bv0 = *(const float4*)(bias + n0);
  float bb[4] = {bv0.x, bv0.y, bv0.z, bv0.w};
  if (POOL == 0) {
#pragma unroll
    for (int i2 = 0; i2 < 4; ++i2) {
      int r = nb + ty * 4 + i2;
      if (r < kNT) {
        float4 o0;
        o0.x = fmaxf(acc[i2][0] + bb[0], 0.f);
        o0.y = fmaxf(acc[i2][1] + bb[1], 0.f);
        o0.z = fmaxf(acc[i2][2] + bb[2], 0.f);
        o0.w = fmaxf(acc[i2][3] + bb[3], 0.f);
        *(float4*)(xout + (size_t)r * kH + n0) = o0;
      }
    }
  } else {
    int rlast = min(nb + 63, kNT - 1);
    int b0 = batch[nb], b1 = batch[rlast];
    if (b0 == b1) {
      float p[4] = {};
#pragma unroll
      for (int i2 = 0; i2 < 4; ++i2) {
        int r = nb + ty * 4 + i2;
        if (r < kNT) {
#pragma unroll
          for (int j2 = 0; j2 < 4; ++j2) p[j2] += fmaxf(acc[i2][j2] + bb[j2], 0.f);
        }
      }
      __syncthreads();
      float* Ls = Ws;  // [16][132]
#pragma unroll
      for (int j2 = 0; j2 < 4; ++j2) Ls[ty * 132 + n0 + j2] = p[j2];
      __syncthreads();
      if (tid < 128) {
        float s = 0.f;
#pragma unroll
        for (int r2 = 0; r2 < 16; ++r2) s += Ls[r2 * 132 + tid];
        atomicAdd(&xg[b0 * kH + tid], s);
      }
    } else {
#pragma unroll
      for (int i2 = 0; i2 < 4; ++i2) {
        int r = nb + ty * 4 + i2;
        if (r < kNT) {
          int br = batch[r];
#pragma unroll
          for (int j2 = 0; j2 < 4; ++j2)
            atomicAdd(&xg[br * kH + n0 + j2], fmaxf(acc[i2][j2] + bb[j2], 0.f));
        }
      }
    }
  }
}

// out[b][o] = concat(xg[b]/cnt[b], xacc[b]/cnte[b]) . mlp_w[o] + mlp_b[o]
__global__ void final_kernel(const float* __restrict__ xg, const int* __restrict__ cnt,
                             const float* __restrict__ xacc, const int* __restrict__ cnte,
                             const float* __restrict__ mw, const float* __restrict__ mb,
                             float* __restrict__ out) {
  int idx = blockIdx.x * blockDim.x + threadIdx.x;
  if (idx >= kB * kOut) return;
  int b = idx / kOut, o = idx % kOut;
  float invg = 1.f / (float)cnt[b];
  float invn = 1.f / (float)cnte[b];
  float acc = mb[o];
  const float* w = mw + (size_t)o * (2 * kH);
  for (int h = 0; h < kH; h++) acc += xg[b * kH + h] * invg * w[h];
  for (int h = 0; h < kH; h++) acc += xacc[b * kH + h] * invn * w[kH + h];
  out[idx] = acc;
}

extern "C" void kernel_launch(void* const* d_in, const int* in_sizes, int n_in,
                              void* d_out, int out_size, void* d_ws, size_t ws_size,
                              hipStream_t stream) {
  const float* node_emb = (const float*)d_in[0];
  const float* edge_emb = (const float*)d_in[1];
  const float* lin_w = (const float*)d_in[2];
  const float* lin_b = (const float*)d_in[3];
  const float* alpha_w = (const float*)d_in[4];
  const float* alpha_b = (const float*)d_in[5];
  const float* beta_w = (const float*)d_in[6];
  const float* beta_b = (const float*)d_in[7];
  const float* wr_w = (const float*)d_in[8];
  const float* wr_b = (const float*)d_in[9];
  const float* conv_w = (const float*)d_in[10];
  const float* conv_b = (const float*)d_in[11];
  const float* mlp_w = (const float*)d_in[12];
  const float* mlp_b = (const float*)d_in[13];
  const int* visit_node = (const int*)d_in[14];
  const int* ehr_nodes = (const int*)d_in[15];
  const int* cat_node_ids = (const int*)d_in[16];
  const int* cat_edge_ids = (const int*)d_in[17];
  const int* edge_index = (const int*)d_in[18];
  const int* batch = (const int*)d_in[19];

  char* ws = (char*)d_ws;
  float* XA = (float*)(ws);                           // 51,200,000
  float* ZP = (float*)(ws);                           // 50,331,648 (dead before XA written)
  float* XB = (float*)(ws + 51200000);                // scratch region
  float* PN = XB;                                     // 768,512 at XB base
  float* VNT = (float*)(ws + 51200000 + 1048576);     // 3,080,192 (ends 55,328,768)
  int* CSN = (int*)(ws + 56000000);                   // 3,200,000
  int* CSRS2 = (int*)(ws + 59200000);                 // 3,200,000
  float* CS1C = (float*)(ws + 62400000);              // 3,200,000
  int* OFF2 = (int*)(ws + 65600000);                  // 400,004
  int* CURSOR2 = (int*)(ws + 66000008);               // 400,000
  int* SPART2 = (int*)(ws + 66400008);                // 2,048
  float* PQ2 = (float*)(ws + 81200000);               // 1,537,024
  float* PS = (float*)(ws + 82800000);                // 768,512
  float* ATTN = (float*)(ws + 102400000);             // 192,128
  float* BETA = (float*)(ws + 102592256);             // 3,840
  float* UC = (float*)(ws + 102596352);               // 1,032
  float* WREL = (float*)(ws + 102597632);             // 16,008
  int* OFF = (int*)(ws + 102613760);                  // 400,004
  int* CURSOR = (int*)(ws + 103014016);               // 400,000 (also DEG)
  int* SPART = (int*)(ws + 103414016);                // 2,048
  float* CS0 = (float*)(ws + 106616064);              // 3,200,000
  float* XG = (float*)(ws + 113016064);               // 8,192
  int* CNT = (int*)(ws + 113024256);                  // 64
  float* XNACC = (float*)(ws + 113024320);            // 8,192
  int* CNTE = (int*)(ws + 113032512);                 // 64

  pn_kernel<<<kNV, kH, 0, stream>>>(node_emb, lin_w, lin_b, conv_w, conv_b, PN, PQ2, PS);
  hipMemsetAsync(XG, 0, 16512, stream);
  xnode_kernel<<<dim3(kB, 12), kH, 0, stream>>>(ehr_nodes, PN, XNACC, CNTE);
  cnt_kernel<<<kNB, 256, 0, stream>>>(batch, CNT);
  uc_kernel<<<1, 256, 0, stream>>>(wr_w, wr_b, lin_w, lin_b, UC);
  wrel_kernel<<<(kL * kNE + 255) / 256, 256, 0, stream>>>(edge_emb, UC, WREL);
  beta_kernel<<<kL * kM, 64, 0, stream>>>(visit_node, beta_w, beta_b, BETA);
  vnt_kernel<<<dim3(kB, kKT), 256, 0, stream>>>(visit_node, VNT);
  zpart_kernel<<<dim3((kNV + 127) / 128, kMZ / 64, kL * kKSZ), 256, 0, stream>>>(VNT, alpha_w,
                                                                                 ZP);
  zsm_kernel<<<(kL * kB * kNV + 255) / 256, 256, 0, stream>>>(ZP, BETA, ATTN);

  hipMemsetAsync(CURSOR, 0, kNT * 4, stream);
  hipMemsetAsync(CURSOR2, 0, kNT * 4, stream);
  hist_kernel<<<(kE + 255) / 256, 256, 0, stream>>>(edge_index, cat_node_ids, batch, ATTN,
                                                    CURSOR, CURSOR2);
  scan1_kernel<<<kNB, 256, 0, stream>>>(CURSOR, OFF, SPART);
  scan2_kernel<<<1, 512, 0, stream>>>(SPART);
  scan3_kernel<<<kNB, 256, 0, stream>>>(OFF, SPART, CURSOR);
  scan1_kernel<<<kNB, 256, 0, stream>>>(CURSOR2, OFF2, SPART2);
  scan2_kernel<<<1, 512, 0, stream>>>(SPART2);
  scan3_kernel<<<kNB, 256, 0, stream>>>(OFF2, SPART2, CURSOR2);
  scatter_kernel<<<(kE + 255) / 256, 256, 0, stream>>>(edge_index, cat_node_ids, cat_edge_ids,
                                                       batch, ATTN, WREL, CURSOR, CSN, CS0,
                                                       CURSOR2, CSRS2, CS1C);

  // layer 1: output-space gather from PQ2/PS tables -> XA (clobbers dead ZP)
  l1_kernel<<<(kNT + 15) / 16, 512, 0, stream>>>(PQ2, PS, cat_node_ids, CSN, CS0, OFF,
                                                 CURSOR, XA);
  // layer 2: gather from XA via compacted positive CSR, fused pool -> XG
  gconv_kernel<1><<<(kNT + 63) / 64, 512, 0, stream>>>(XA, XA, CSRS2, CS1C, OFF2, CURSOR2,
                                                       nullptr, conv_w + (size_t)kH * kD,
                                                       conv_b + kH, nullptr, XG, batch);

  final_kernel<<<2, 256, 0, stream>>>(XG, CNT, XNACC, CNTE, mlp_w, mlp_b, (float*)d_out);
}

// Round 21
// 415.145 us; speedup vs baseline: 1.0084x; 1.0084x over previous
//
#include <hip/hip_runtime.h>
#include <math.h>

namespace {
constexpr int kB = 16, kV = 30, kNV = 1501, kNE = 2001, kH = 128, kD = 128,
              kL = 2, kOut = 25, kNT = 100000, kE = 800000, kM = kB * kV;
constexpr int kNB = (kNT + 255) / 256;  // 391 scan blocks
constexpr int kKT = 47;                 // k-chunks of 32 (47*32 = 1504 >= 1501)
constexpr int kKP = kKT * 32;           // padded K = 1504
constexpr int kKSZ = 6;                 // split-K blocks for z
constexpr int kKCH = 8;                 // k-chunks per split slice (6*8=48 >= 47)
constexpr int kNVZ = 1536;              // padded n-stride for z partials
constexpr int kMZ = 512;                // padded M = 16 b x 32 v
}

// PN[n] = node_emb[n]@lin_w^T + lin_b; PQ2[n] = relu(PN[n])@W1^T,
// PQ2[kNV+n] = relu(-PN[n])@W1^T; PS[n] = PN[n]@W1^T + b1.
__global__ void pn_kernel(const float* __restrict__ emb, const float* __restrict__ lw,
                          const float* __restrict__ lb, const float* __restrict__ cw,
                          const float* __restrict__ cb, float* __restrict__ pn,
                          float* __restrict__ pq2, float* __restrict__ ps) {
  int n = blockIdx.x, h = threadIdx.x;
  __shared__ float erow[kD];
  __shared__ float row[kD];
  erow[h] = emb[(size_t)n * kD + h];
  __syncthreads();
  float acc = lb[h];
#pragma unroll 8
  for (int d = 0; d < kD; d++) acc += erow[d] * lw[h * kD + d];
  pn[(size_t)n * kH + h] = acc;
  row[h] = acc;
  __syncthreads();
  float ap = 0.f, am = 0.f, aps = cb[h];
  const float* wr = cw + h * kD;
#pragma unroll 8
  for (int d = 0; d < kD; d++) {
    float r = row[d];
    float w = wr[d];
    ap = fmaf(fmaxf(r, 0.f), w, ap);
    am = fmaf(fmaxf(-r, 0.f), w, am);
    aps = fmaf(r, w, aps);
  }
  pq2[(size_t)n * kH + h] = ap;
  pq2[(size_t)(kNV + n) * kH + h] = am;
  ps[(size_t)n * kH + h] = aps;
}

// node branch partials
__global__ void xnode_kernel(const int* __restrict__ ehr, const float* __restrict__ pn,
                             float* __restrict__ xacc, int* __restrict__ cnte) {
  int b = blockIdx.x;
  int c = blockIdx.y;
  int h = threadIdx.x;
  int n0 = c * 128;
  __shared__ int flags[128];
  int gn = n0 + h;
  flags[h] = (gn < kNV) ? ehr[(size_t)b * kNV + gn] : 0;
  __syncthreads();
  float acc = 0.f;
  int cnt = 0;
  int n1 = min(n0 + 128, kNV);
  for (int n = n0; n < n1; ++n) {
    if (flags[n - n0]) {
      acc += pn[(size_t)n * kH + h];
      cnt++;
    }
  }
  atomicAdd(&xacc[b * kH + h], acc);
  if (h == 0) atomicAdd(&cnte[b], cnt);
}

// u[l][d] = sum_h wr_w[l][h]*lin_w[h][d] ; c[l] = wr_w[l].lin_b + wr_b[l]
__global__ void uc_kernel(const float* __restrict__ wrw, const float* __restrict__ wrb,
                          const float* __restrict__ lw, const float* __restrict__ lb,
                          float* __restrict__ uc) {
  int t = threadIdx.x;
  int l = t >> 7, d = t & 127;
  float s = 0.f;
  for (int h = 0; h < kH; h++) s += wrw[l * kH + h] * lw[h * kD + d];
  uc[t] = s;
  if (t < kL) {
    float c = wrb[t];
    for (int h = 0; h < kH; h++) c += wrw[t * kH + h] * lb[h];
    uc[256 + t] = c;
  }
}

// wrel[l][r] = sigmoid(edge_emb[r] . u[l] + c[l])
__global__ void wrel_kernel(const float* __restrict__ eemb, const float* __restrict__ uc,
                            float* __restrict__ wrel) {
  int idx = blockIdx.x * blockDim.x + threadIdx.x;
  if (idx >= kL * kNE) return;
  int l = idx / kNE, r = idx % kNE;
  float z = uc[256 + l];
  const float* u = uc + l * 128;
  const float* er = eemb + (size_t)r * kD;
  for (int d = 0; d < kD; d++) z += er[d] * u[d];
  wrel[idx] = 1.f / (1.f + expf(-z));
}

// beta[l][b*V+v] = tanh(vn[b,v,:].beta_w[l] + beta_b[l]) * exp(0.01*(V-v))
__global__ void beta_kernel(const int* __restrict__ vn, const float* __restrict__ bw,
                            const float* __restrict__ bb, float* __restrict__ beta) {
  int blk = blockIdx.x;
  int l = blk / kM, r = blk % kM;
  int v = r % kV;
  int lane = threadIdx.x;
  const int* row = vn + (size_t)r * kNV;
  const float* w = bw + (size_t)l * kNV;
  float s = 0.f;
  for (int k = lane; k < kNV; k += 64) s += (float)row[k] * w[k];
  for (int off = 32; off > 0; off >>= 1) s += __shfl_down(s, off, 64);
  if (lane == 0) {
    float lam = expf(0.01f * (float)(kV - v));
    beta[blk] = tanhf(s + bb[l]) * lam;
  }
}

// VNTALL[k][m] = (float)vn[b][v][k], m = b*32+v (512 cols), k padded to 1504.
__global__ void vnt_kernel(const int* __restrict__ vn, float* __restrict__ vnt) {
  int b = blockIdx.x, kt = blockIdx.y;
  int k0 = kt * 32;
  int tid = threadIdx.x;  // 256
  __shared__ float t[32][33];  // t[v][kk]
#pragma unroll
  for (int i = 0; i < 4; ++i) {
    int e = tid + i * 256;  // 1024 = 32v x 32k
    int v = e >> 5, kk = e & 31;
    int gk = k0 + kk;
    t[v][kk] = (v < kV && gk < kNV) ? (float)vn[(size_t)(b * kV + v) * kNV + gk] : 0.f;
  }
  __syncthreads();
  float* out = vnt + (size_t)k0 * kMZ + b * 32;
#pragma unroll
  for (int i = 0; i < 4; ++i) {
    int e = tid + i * 256;
    int kk = e >> 5, v = e & 31;
    out[(size_t)kk * kMZ + v] = t[v][kk];
  }
}

// Split-K partial z: zp[ks][l][m][n] = sum_{k in slice} VNTALL[k][m]*aw[l][n][k]
// 128m x 128n tile, 8x8 per thread (better FMA:LDS ratio), grid (12,4,12)=576.
__global__ void zpart_kernel(const float* __restrict__ vntall, const float* __restrict__ aw,
                             float* __restrict__ zp) {
  const int zidx = blockIdx.z;
  const int l = zidx / kKSZ, ks = zidx % kKSZ;
  const int mb = blockIdx.y * 128;
  const int nb = blockIdx.x * 128;
  const int tid = threadIdx.x;  // 256
  __shared__ float As[32 * 128];  // 16 KB [kk][m], k-major (broadcast reads)
  __shared__ float Bs[32 * 128];  // 16 KB [kk][n], XOR granule-swizzled
  const float* awl = aw + (size_t)l * kNV * kNV;
  const int tx = tid & 15;   // n pair-granule: cols tx*4 and 64+tx*4
  const int ty = tid >> 4;   // m granule: rows ty*8
  const int snn = tid >> 3;  // Bs staging n within 32-row group
  const int sk4 = (tid & 7) * 4;
  const int ct0 = ks * kKCH;
  const int ct1 = min(ct0 + kKCH, kKT);
  float acc[8][8] = {};
  for (int kt = ct0; kt < ct1; ++kt) {
    const int k0 = kt * 32;
    __syncthreads();
    // ---- stage As: 32k x 128m, plain float4 copies (both k-major) ----
#pragma unroll
    for (int i = 0; i < 4; ++i) {
      int e = tid + i * 256;  // 1024 float4
      int kk = e >> 5, mq = (e & 31) * 4;
      *(float4*)&As[kk * 128 + mq] =
          *(const float4*)(vntall + (size_t)(k0 + kk) * kMZ + mb + mq);
    }
    // ---- stage Bs: 128n x 32k with XOR granule swizzle ----
    if (k0 + 32 <= kNV) {
#pragma unroll
      for (int i = 0; i < 4; ++i) {
        int nn = snn + 32 * i;
        int gn = nb + nn;
        float4 a = (gn < kNV) ? *(const float4*)(awl + (size_t)gn * kNV + k0 + sk4)
                              : float4{0.f, 0.f, 0.f, 0.f};
        float av[4] = {a.x, a.y, a.z, a.w};
#pragma unroll
        for (int j = 0; j < 4; ++j) {
          int kk = sk4 + j;
          int g = (nn >> 2) ^ (kk >> 2);
          Bs[kk * 128 + (g << 2) + (nn & 3)] = av[j];
        }
      }
    } else {
#pragma unroll
      for (int i = 0; i < 4; ++i) {
        int nn = snn + 32 * i;
        int gn = nb + nn;
#pragma unroll
        for (int j = 0; j < 4; ++j) {
          int kk = sk4 + j;
          int gk = k0 + kk;
          float v = (gn < kNV && gk < kNV) ? awl[(size_t)gn * kNV + gk] : 0.f;
          int g = (nn >> 2) ^ (kk >> 2);
          Bs[kk * 128 + (g << 2) + (nn & 3)] = v;
        }
      }
    }
    __syncthreads();
#pragma unroll 2
    for (int kk = 0; kk < 32; ++kk) {
      float4 a0 = *(const float4*)&As[kk * 128 + ty * 8];
      float4 a1 = *(const float4*)&As[kk * 128 + ty * 8 + 4];
      float4 b0 = *(const float4*)&Bs[kk * 128 + ((tx ^ (kk >> 2)) << 2)];
      float4 b1 = *(const float4*)&Bs[kk * 128 + (((tx + 16) ^ (kk >> 2)) << 2)];
      float am[8] = {a0.x, a0.y, a0.z, a0.w, a1.x, a1.y, a1.z, a1.w};
      float bn[8] = {b0.x, b0.y, b0.z, b0.w, b1.x, b1.y, b1.z, b1.w};
#pragma unroll
      for (int i2 = 0; i2 < 8; ++i2)
#pragma unroll
        for (int j2 = 0; j2 < 8; ++j2) acc[i2][j2] = fmaf(am[i2], bn[j2], acc[i2][j2]);
    }
  }
  float* zb = zp + (size_t)(ks * kL + l) * kMZ * kNVZ;
#pragma unroll
  for (int i2 = 0; i2 < 8; ++i2) {
    int m = mb + ty * 8 + i2;
    *(float4*)&zb[(size_t)m * kNVZ + nb + tx * 4] =
        float4{acc[i2][0], acc[i2][1], acc[i2][2], acc[i2][3]};
    *(float4*)&zb[(size_t)m * kNVZ + nb + 64 + tx * 4] =
        float4{acc[i2][4], acc[i2][5], acc[i2][6], acc[i2][7]};
  }
}

// attn[l][b][n] = sum_v softmax_v(sum_ks zp) * beta[l][b][v]
__global__ void zsm_kernel(const float* __restrict__ zp, const float* __restrict__ beta,
                           float* __restrict__ attn) {
  int idx = blockIdx.x * blockDim.x + threadIdx.x;
  if (idx >= kL * kB * kNV) return;
  int n = idx % kNV;
  int lb_ = idx / kNV;  // l*kB + b
  int l = lb_ / kB, b = lb_ % kB;
  const size_t PSTR = (size_t)kL * kMZ * kNVZ;  // partial stride
  const float* p = zp + ((size_t)l * kMZ + b * 32) * kNVZ + n;
  float zz[kV];
  float m = -1e30f;
#pragma unroll
  for (int v = 0; v < kV; ++v) {
    size_t o = (size_t)v * kNVZ;
    float s = 0.f;
#pragma unroll
    for (int q = 0; q < kKSZ; ++q) s += p[o + (size_t)q * PSTR];
    zz[v] = s;
    m = fmaxf(m, s);
  }
  float s = 0.f, num = 0.f;
  const float* bet = beta + lb_ * kV;
#pragma unroll
  for (int v = 0; v < kV; ++v) {
    float e = expf(zz[v] - m);
    s += e;
    num += e * bet[v];
  }
  attn[idx] = num / s;
}

// ---- CSR build ----
__global__ void hist_kernel(const int* __restrict__ ei, const int* __restrict__ nid,
                            const int* __restrict__ batch, const float* __restrict__ attn,
                            int* __restrict__ deg, int* __restrict__ deg2) {
  int e = blockIdx.x * blockDim.x + threadIdx.x;
  if (e >= kE) return;
  int d = ei[kE + e];
  atomicAdd(&deg[d], 1);
  int s = ei[e];
  float a1 = attn[(size_t)kB * kNV + batch[s] * kNV + nid[s]];
  if (a1 > 0.f) atomicAdd(&deg2[d], 1);
}

__global__ void scan1_kernel(const int* __restrict__ deg, int* __restrict__ off,
                             int* __restrict__ part) {
  int t = threadIdx.x, i = blockIdx.x * 256 + t;
  int v = (i < kNT) ? deg[i] : 0;
  __shared__ int sm[256];
  sm[t] = v;
  __syncthreads();
  for (int o = 1; o < 256; o <<= 1) {
    int x = (t >= o) ? sm[t - o] : 0;
    __syncthreads();
    sm[t] += x;
    __syncthreads();
  }
  if (i < kNT) off[i] = sm[t] - v;
  if (t == 255) part[blockIdx.x] = sm[255];
}

__global__ void scan2_kernel(int* __restrict__ part) {
  int t = threadIdx.x;  // 512
  int v = (t < kNB) ? part[t] : 0;
  __shared__ int sm[512];
  sm[t] = v;
  __syncthreads();
  for (int o = 1; o < 512; o <<= 1) {
    int x = (t >= o) ? sm[t - o] : 0;
    __syncthreads();
    sm[t] += x;
    __syncthreads();
  }
  if (t < kNB) part[t] = sm[t] - v;
}

__global__ void scan3_kernel(int* __restrict__ off, const int* __restrict__ part,
                             int* __restrict__ cursor) {
  int i = blockIdx.x * 256 + threadIdx.x;
  if (i >= kNT) return;
  int o = off[i] + part[blockIdx.x];
  off[i] = o;
  cursor[i] = o;
}

// counts per batch segment: per-block LDS histogram, 16 global atomics/block
__global__ void cnt_kernel(const int* __restrict__ batch, int* __restrict__ cnt) {
  __shared__ int hist[kB];
  int t = threadIdx.x;
  if (t < kB) hist[t] = 0;
  __syncthreads();
  int i = blockIdx.x * blockDim.x + t;
  if (i < kNT) atomicAdd(&hist[batch[i]], 1);
  __syncthreads();
  if (t < kB && hist[t]) atomicAdd(&cnt[t], hist[t]);
}

// scatter: layer-1 CSR (csn sign-folded row, |cs0|w0) + compacted positive CSR
__global__ void scatter_kernel(const int* __restrict__ ei, const int* __restrict__ nid,
                               const int* __restrict__ eid, const int* __restrict__ batch,
                               const float* __restrict__ attn, const float* __restrict__ wrel,
                               int* __restrict__ cursor, int* __restrict__ csn,
                               float* __restrict__ cs0, int* __restrict__ cursor2,
                               int* __restrict__ csrc2, float* __restrict__ cs1c) {
  int e = blockIdx.x * blockDim.x + threadIdx.x;
  if (e >= kE) return;
  int s = ei[e], d = ei[kE + e];
  int b = batch[s], n = nid[s], r = eid[e];
  float a0 = attn[(size_t)b * kNV + n];
  float a1 = attn[(size_t)kB * kNV + b * kNV + n];
  float w0 = wrel[r], w1 = wrel[kNE + r];
  int pos = atomicAdd(&cursor[d], 1);
  csn[pos] = n + ((a0 > 0.f) ? 0 : kNV);
  cs0[pos] = fabsf(a0) * w0;
  if (a1 > 0.f) {
    int p2 = atomicAdd(&cursor2[d], 1);
    csrc2[p2] = s;
    cs1c[p2] = a1 * w1;
  }
}

#define GACC(A, V, C)                                  \
  A.x = fmaf(V.x, C, A.x); A.y = fmaf(V.y, C, A.y);    \
  A.z = fmaf(V.z, C, A.z); A.w = fmaf(V.w, C, A.w);

// Layer 1 in OUTPUT space: xa[node] = relu(PS[nid[node]] + sum_e cs0*PQ2[csn]).
__global__ void l1_kernel(const float* __restrict__ pq2, const float* __restrict__ psTab,
                          const int* __restrict__ nid, const int* __restrict__ csn,
                          const float* __restrict__ cs0, const int* __restrict__ off,
                          const int* __restrict__ endv, float* __restrict__ xa) {
  const int tid = threadIdx.x;  // 512
  const int lane = tid & 63;
  const int sub = lane >> 5, sl = lane & 31;
  const int hw = (tid >> 6) * 2 + sub;  // half-wave 0..15
  int node = blockIdx.x * 16 + hw;
  if (node >= kNT) return;
  const float4* x4 = (const float4*)pq2;
  float4 a0 = ((const float4*)psTab)[(size_t)nid[node] * 32 + sl];
  float4 a1 = {0.f, 0.f, 0.f, 0.f};
  float4 a2 = {0.f, 0.f, 0.f, 0.f};
  float4 a3 = {0.f, 0.f, 0.f, 0.f};
  int j0 = off[node], j1 = endv[node];
  for (int base = j0; base < j1; base += 32) {
    int n = j1 - base;
    if (n > 32) n = 32;
    int sidx = 0;
    float ssc = 0.f;
    if (sl < n) {
      sidx = csn[base + sl];
      ssc = cs0[base + sl];
    }
    int t = 0;
    for (; t + 8 <= n; t += 8) {
      int s0 = __shfl(sidx, sub * 32 + t + 0, 64);
      int s1 = __shfl(sidx, sub * 32 + t + 1, 64);
      int s2 = __shfl(sidx, sub * 32 + t + 2, 64);
      int s3 = __shfl(sidx, sub * 32 + t + 3, 64);
      int s4i = __shfl(sidx, sub * 32 + t + 4, 64);
      int s5 = __shfl(sidx, sub * 32 + t + 5, 64);
      int s6 = __shfl(sidx, sub * 32 + t + 6, 64);
      int s7 = __shfl(sidx, sub * 32 + t + 7, 64);
      float c0 = __shfl(ssc, sub * 32 + t + 0, 64);
      float c1 = __shfl(ssc, sub * 32 + t + 1, 64);
      float c2 = __shfl(ssc, sub * 32 + t + 2, 64);
      float c3 = __shfl(ssc, sub * 32 + t + 3, 64);
      float c4 = __shfl(ssc, sub * 32 + t + 4, 64);
      float c5 = __shfl(ssc, sub * 32 + t + 5, 64);
      float c6 = __shfl(ssc, sub * 32 + t + 6, 64);
      float c7 = __shfl(ssc, sub * 32 + t + 7, 64);
      float4 v0 = x4[(size_t)s0 * 32 + sl];
      float4 v1 = x4[(size_t)s1 * 32 + sl];
      float4 v2 = x4[(size_t)s2 * 32 + sl];
      float4 v3 = x4[(size_t)s3 * 32 + sl];
      float4 v4 = x4[(size_t)s4i * 32 + sl];
      float4 v5 = x4[(size_t)s5 * 32 + sl];
      float4 v6 = x4[(size_t)s6 * 32 + sl];
      float4 v7 = x4[(size_t)s7 * 32 + sl];
      GACC(a0, v0, c0);
      GACC(a1, v1, c1);
      GACC(a2, v2, c2);
      GACC(a3, v3, c3);
      GACC(a0, v4, c4);
      GACC(a1, v5, c5);
      GACC(a2, v6, c6);
      GACC(a3, v7, c7);
    }
    for (; t + 4 <= n; t += 4) {
      int s0 = __shfl(sidx, sub * 32 + t + 0, 64);
      int s1 = __shfl(sidx, sub * 32 + t + 1, 64);
      int s2 = __shfl(sidx, sub * 32 + t + 2, 64);
      int s3 = __shfl(sidx, sub * 32 + t + 3, 64);
      float c0 = __shfl(ssc, sub * 32 + t + 0, 64);
      float c1 = __shfl(ssc, sub * 32 + t + 1, 64);
      float c2 = __shfl(ssc, sub * 32 + t + 2, 64);
      float c3 = __shfl(ssc, sub * 32 + t + 3, 64);
      float4 v0 = x4[(size_t)s0 * 32 + sl];
      float4 v1 = x4[(size_t)s1 * 32 + sl];
      float4 v2 = x4[(size_t)s2 * 32 + sl];
      float4 v3 = x4[(size_t)s3 * 32 + sl];
      GACC(a0, v0, c0);
      GACC(a1, v1, c1);
      GACC(a2, v2, c2);
      GACC(a3, v3, c3);
    }
    for (; t < n; ++t) {
      int s = __shfl(sidx, sub * 32 + t, 64);
      float sc = __shfl(ssc, sub * 32 + t, 64);
      float4 xv = x4[(size_t)s * 32 + sl];
      GACC(a0, xv, sc);
    }
  }
  float4 o;
  o.x = fmaxf(a0.x + a1.x + a2.x + a3.x, 0.f);
  o.y = fmaxf(a0.y + a1.y + a2.y + a3.y, 0.f);
  o.z = fmaxf(a0.z + a1.z + a2.z + a3.z, 0.f);
  o.w = fmaxf(a0.w + a1.w + a2.w + a3.w, 0.f);
  ((float4*)xa)[(size_t)node * 32 + sl] = o;
}

// Fused gather+conv for layer 2 (pool path), 512 threads/block, pure-fma edges.
template <int POOL>
__global__ void gconv_kernel(const float* __restrict__ srcTab,
                             const float* __restrict__ selfTab,
                             const int* __restrict__ cidx, const float* __restrict__ cscal,
                             const int* __restrict__ off, const int* __restrict__ endv,
                             const int* __restrict__ selfIdx, const float* __restrict__ w,
                             const float* __restrict__ bias, float* __restrict__ xout,
                             float* __restrict__ xg, const int* __restrict__ batch) {
  const int nb = blockIdx.x * 64;
  const int tid = threadIdx.x;  // 512
  __shared__ float As[128 * 64];
  __shared__ float Ws[32 * 132];
  const int wv = tid >> 6;
  const int lane = tid & 63;
  const int sub = lane >> 5, sl = lane & 31;
  const int hw = wv * 2 + sub;
  const float4* x4 = (const float4*)srcTab;
  const float4* s4 = (const float4*)selfTab;
  for (int p = 0; p < 4; ++p) {
    int nl = p * 16 + hw;
    int node = nb + nl;
    if (node < kNT) {
      int selfRow = selfIdx ? selfIdx[node] : node;
      float4 a0 = s4[(size_t)selfRow * 32 + sl];
      float4 a1 = {0.f, 0.f, 0.f, 0.f};
      float4 a2 = {0.f, 0.f, 0.f, 0.f};
      float4 a3 = {0.f, 0.f, 0.f, 0.f};
      int j0 = off[node], j1 = endv[node];
      for (int base = j0; base < j1; base += 32) {
        int n = j1 - base;
        if (n > 32) n = 32;
        int sidx = 0;
        float ssc = 0.f;
        if (sl < n) {
          sidx = cidx[base + sl];
          ssc = cscal[base + sl];
        }
        int t = 0;
        for (; t + 8 <= n; t += 8) {
          int s0 = __shfl(sidx, sub * 32 + t + 0, 64);
          int s1 = __shfl(sidx, sub * 32 + t + 1, 64);
          int s2 = __shfl(sidx, sub * 32 + t + 2, 64);
          int s3 = __shfl(sidx, sub * 32 + t + 3, 64);
          int s4i = __shfl(sidx, sub * 32 + t + 4, 64);
          int s5 = __shfl(sidx, sub * 32 + t + 5, 64);
          int s6 = __shfl(sidx, sub * 32 + t + 6, 64);
          int s7 = __shfl(sidx, sub * 32 + t + 7, 64);
          float c0 = __shfl(ssc, sub * 32 + t + 0, 64);
          float c1 = __shfl(ssc, sub * 32 + t + 1, 64);
          float c2 = __shfl(ssc, sub * 32 + t + 2, 64);
          float c3 = __shfl(ssc, sub * 32 + t + 3, 64);
          float c4 = __shfl(ssc, sub * 32 + t + 4, 64);
          float c5 = __shfl(ssc, sub * 32 + t + 5, 64);
          float c6 = __shfl(ssc, sub * 32 + t + 6, 64);
          float c7 = __shfl(ssc, sub * 32 + t + 7, 64);
          float4 v0 = x4[(size_t)s0 * 32 + sl];
          float4 v1 = x4[(size_t)s1 * 32 + sl];
          float4 v2 = x4[(size_t)s2 * 32 + sl];
          float4 v3 = x4[(size_t)s3 * 32 + sl];
          float4 v4 = x4[(size_t)s4i * 32 + sl];
          float4 v5 = x4[(size_t)s5 * 32 + sl];
          float4 v6 = x4[(size_t)s6 * 32 + sl];
          float4 v7 = x4[(size_t)s7 * 32 + sl];
          GACC(a0, v0, c0);
          GACC(a1, v1, c1);
          GACC(a2, v2, c2);
          GACC(a3, v3, c3);
          GACC(a0, v4, c4);
          GACC(a1, v5, c5);
          GACC(a2, v6, c6);
          GACC(a3, v7, c7);
        }
        for (; t + 4 <= n; t += 4) {
          int s0 = __shfl(sidx, sub * 32 + t + 0, 64);
          int s1 = __shfl(sidx, sub * 32 + t + 1, 64);
          int s2 = __shfl(sidx, sub * 32 + t + 2, 64);
          int s3 = __shfl(sidx, sub * 32 + t + 3, 64);
          float c0 = __shfl(ssc, sub * 32 + t + 0, 64);
          float c1 = __shfl(ssc, sub * 32 + t + 1, 64);
          float c2 = __shfl(ssc, sub * 32 + t + 2, 64);
          float c3 = __shfl(ssc, sub * 32 + t + 3, 64);
          float4 v0 = x4[(size_t)s0 * 32 + sl];
          float4 v1 = x4[(size_t)s1 * 32 + sl];
          float4 v2 = x4[(size_t)s2 * 32 + sl];
          float4 v3 = x4[(size_t)s3 * 32 + sl];
          GACC(a0, v0, c0);
          GACC(a1, v1, c1);
          GACC(a2, v2, c2);
          GACC(a3, v3, c3);
        }
        for (; t < n; ++t) {
          int s = __shfl(sidx, sub * 32 + t, 64);
          float sc = __shfl(ssc, sub * 32 + t, 64);
          float4 xv = x4[(size_t)s * 32 + sl];
          GACC(a0, xv, sc);
        }
      }
      float av[4] = {a0.x + a1.x + a2.x + a3.x, a0.y + a1.y + a2.y + a3.y,
                     a0.z + a1.z + a2.z + a3.z, a0.w + a1.w + a2.w + a3.w};
#pragma unroll
      for (int j = 0; j < 4; ++j) {
        int d = sl * 4 + j;
        int g = (nl >> 2) ^ (sl & 15);
        As[d * 64 + (g << 2) + (nl & 3)] = av[j];
      }
    }
  }
  __syncthreads();
  const int tx = tid & 31, ty = tid >> 5;
  const int n0 = tx * 4;
  float acc[4][4] = {};
  for (int kc = 0; kc < 4; ++kc) {
    if (kc) __syncthreads();
#pragma unroll
    for (int i = 0; i < 2; ++i) {
      int fi = tid + i * 512;
      int hh = fi >> 3, c4 = (fi & 7) * 4;
      float4 v = *(const float4*)(w + (size_t)hh * kD + kc * 32 + c4);
      Ws[(c4 + 0) * 132 + hh] = v.x;
      Ws[(c4 + 1) * 132 + hh] = v.y;
      Ws[(c4 + 2) * 132 + hh] = v.z;
      Ws[(c4 + 3) * 132 + hh] = v.w;
    }
    __syncthreads();
#pragma unroll
    for (int dd = 0; dd < 32; ++dd) {
      int d = kc * 32 + dd;
      float4 a = *(const float4*)&As[d * 64 + ((ty ^ ((d >> 2) & 15)) << 2)];
      float4 b0 = *(const float4*)&Ws[dd * 132 + n0];
      float am[4] = {a.x, a.y, a.z, a.w};
      float bn[4] = {b0.x, b0.y, b0.z, b0.w};
#pragma unroll
      for (int i2 = 0; i2 < 4; ++i2)
#pragma unroll
        for (int j2 = 0; j2 < 4; ++j2) acc[i2][j2] += am[i2] * bn[j2];
    }
  }
  float4 bv0 = *(const float4*)(bias + n0);
  float bb[4] = {bv0.x, bv0.y, bv0.z, bv0.w};
  if (POOL == 0) {
#pragma unroll
    for (int i2 = 0; i2 < 4; ++i2) {
      int r = nb + ty * 4 + i2;
      if (r < kNT) {
        float4 o0;
        o0.x = fmaxf(acc[i2][0] + bb[0], 0.f);
        o0.y = fmaxf(acc[i2][1] + bb[1], 0.f);
        o0.z = fmaxf(acc[i2][2] + bb[2], 0.f);
        o0.w = fmaxf(acc[i2][3] + bb[3], 0.f);
        *(float4*)(xout + (size_t)r * kH + n0) = o0;
      }
    }
  } else {
    int rlast = min(nb + 63, kNT - 1);
    int b0 = batch[nb], b1 = batch[rlast];
    if (b0 == b1) {
      float p[4] = {};
#pragma unroll
      for (int i2 = 0; i2 < 4; ++i2) {
        int r = nb + ty * 4 + i2;
        if (r < kNT) {
#pragma unroll
          for (int j2 = 0; j2 < 4; ++j2) p[j2] += fmaxf(acc[i2][j2] + bb[j2], 0.f);
        }
      }
      __syncthreads();
      float* Ls = Ws;  // [16][132]
#pragma unroll
      for (int j2 = 0; j2 < 4; ++j2) Ls[ty * 132 + n0 + j2] = p[j2];
      __syncthreads();
      if (tid < 128) {
        float s = 0.f;
#pragma unroll
        for (int r2 = 0; r2 < 16; ++r2) s += Ls[r2 * 132 + tid];
        atomicAdd(&xg[b0 * kH + tid], s);
      }
    } else {
#pragma unroll
      for (int i2 = 0; i2 < 4; ++i2) {
        int r = nb + ty * 4 + i2;
        if (r < kNT) {
          int br = batch[r];
#pragma unroll
          for (int j2 = 0; j2 < 4; ++j2)
            atomicAdd(&xg[br * kH + n0 + j2], fmaxf(acc[i2][j2] + bb[j2], 0.f));
        }
      }
    }
  }
}

// out[b][o] = concat(xg[b]/cnt[b], xacc[b]/cnte[b]) . mlp_w[o] + mlp_b[o]
__global__ void final_kernel(const float* __restrict__ xg, const int* __restrict__ cnt,
                             const float* __restrict__ xacc, const int* __restrict__ cnte,
                             const float* __restrict__ mw, const float* __restrict__ mb,
                             float* __restrict__ out) {
  int idx = blockIdx.x * blockDim.x + threadIdx.x;
  if (idx >= kB * kOut) return;
  int b = idx / kOut, o = idx % kOut;
  float invg = 1.f / (float)cnt[b];
  float invn = 1.f / (float)cnte[b];
  float acc = mb[o];
  const float* w = mw + (size_t)o * (2 * kH);
  for (int h = 0; h < kH; h++) acc += xg[b * kH + h] * invg * w[h];
  for (int h = 0; h < kH; h++) acc += xacc[b * kH + h] * invn * w[kH + h];
  out[idx] = acc;
}

extern "C" void kernel_launch(void* const* d_in, const int* in_sizes, int n_in,
                              void* d_out, int out_size, void* d_ws, size_t ws_size,
                              hipStream_t stream) {
  const float* node_emb = (const float*)d_in[0];
  const float* edge_emb = (const float*)d_in[1];
  const float* lin_w = (const float*)d_in[2];
  const float* lin_b = (const float*)d_in[3];
  const float* alpha_w = (const float*)d_in[4];
  const float* alpha_b = (const float*)d_in[5];
  const float* beta_w = (const float*)d_in[6];
  const float* beta_b = (const float*)d_in[7];
  const float* wr_w = (const float*)d_in[8];
  const float* wr_b = (const float*)d_in[9];
  const float* conv_w = (const float*)d_in[10];
  const float* conv_b = (const float*)d_in[11];
  const float* mlp_w = (const float*)d_in[12];
  const float* mlp_b = (const float*)d_in[13];
  const int* visit_node = (const int*)d_in[14];
  const int* ehr_nodes = (const int*)d_in[15];
  const int* cat_node_ids = (const int*)d_in[16];
  const int* cat_edge_ids = (const int*)d_in[17];
  const int* edge_index = (const int*)d_in[18];
  const int* batch = (const int*)d_in[19];

  char* ws = (char*)d_ws;
  float* XA = (float*)(ws);                           // 51,200,000
  float* XB = (float*)(ws + 51200000);                // scratch region
  float* PN = XB;                                     // 768,512 at XB base
  float* VNT = (float*)(ws + 51200000 + 1048576);     // 3,080,192 (ends 55,328,768)
  float* ZP = (float*)(ws + 56000000);                // 37,748,736 (ends 93,748,736)
  int* CSN = (int*)(ws + 56000000);                   // 3,200,000 (dead-ZP after zsm)
  int* CSRS2 = (int*)(ws + 59200000);                 // 3,200,000
  float* CS1C = (float*)(ws + 62400000);              // 3,200,000
  int* OFF2 = (int*)(ws + 65600000);                  // 400,004
  int* CURSOR2 = (int*)(ws + 66000008);               // 400,000
  int* SPART2 = (int*)(ws + 66400008);                // 2,048
  float* PQ2 = (float*)(ws + 94000000);               // 1,537,024 (outside ZP span)
  float* PS = (float*)(ws + 95600000);                // 768,512
  float* ATTN = (float*)(ws + 102400000);             // 192,128
  float* BETA = (float*)(ws + 102592256);             // 3,840
  float* UC = (float*)(ws + 102596352);               // 1,032
  float* WREL = (float*)(ws + 102597632);             // 16,008
  int* OFF = (int*)(ws + 102613760);                  // 400,004
  int* CURSOR = (int*)(ws + 103014016);               // 400,000 (also DEG)
  int* SPART = (int*)(ws + 103414016);                // 2,048
  float* CS0 = (float*)(ws + 106616064);              // 3,200,000
  float* XG = (float*)(ws + 113016064);               // 8,192
  int* CNT = (int*)(ws + 113024256);                  // 64
  float* XNACC = (float*)(ws + 113024320);            // 8,192
  int* CNTE = (int*)(ws + 113032512);                 // 64

  pn_kernel<<<kNV, kH, 0, stream>>>(node_emb, lin_w, lin_b, conv_w, conv_b, PN, PQ2, PS);
  hipMemsetAsync(XG, 0, 16512, stream);
  xnode_kernel<<<dim3(kB, 12), kH, 0, stream>>>(ehr_nodes, PN, XNACC, CNTE);
  cnt_kernel<<<kNB, 256, 0, stream>>>(batch, CNT);
  uc_kernel<<<1, 256, 0, stream>>>(wr_w, wr_b, lin_w, lin_b, UC);
  wrel_kernel<<<(kL * kNE + 255) / 256, 256, 0, stream>>>(edge_emb, UC, WREL);
  beta_kernel<<<kL * kM, 64, 0, stream>>>(visit_node, beta_w, beta_b, BETA);
  vnt_kernel<<<dim3(kB, kKT), 256, 0, stream>>>(visit_node, VNT);
  zpart_kernel<<<dim3((kNV + 127) / 128, kMZ / 128, kL * kKSZ), 256, 0, stream>>>(VNT, alpha_w,
                                                                                  ZP);
  zsm_kernel<<<(kL * kB * kNV + 255) / 256, 256, 0, stream>>>(ZP, BETA, ATTN);

  hipMemsetAsync(CURSOR, 0, kNT * 4, stream);
  hipMemsetAsync(CURSOR2, 0, kNT * 4, stream);
  hist_kernel<<<(kE + 255) / 256, 256, 0, stream>>>(edge_index, cat_node_ids, batch, ATTN,
                                                    CURSOR, CURSOR2);
  scan1_kernel<<<kNB, 256, 0, stream>>>(CURSOR, OFF, SPART);
  scan2_kernel<<<1, 512, 0, stream>>>(SPART);
  scan3_kernel<<<kNB, 256, 0, stream>>>(OFF, SPART, CURSOR);
  scan1_kernel<<<kNB, 256, 0, stream>>>(CURSOR2, OFF2, SPART2);
  scan2_kernel<<<1, 512, 0, stream>>>(SPART2);
  scan3_kernel<<<kNB, 256, 0, stream>>>(OFF2, SPART2, CURSOR2);
  scatter_kernel<<<(kE + 255) / 256, 256, 0, stream>>>(edge_index, cat_node_ids, cat_edge_ids,
                                                       batch, ATTN, WREL, CURSOR, CSN, CS0,
                                                       CURSOR2, CSRS2, CS1C);

  // layer 1: output-space gather from PQ2/PS tables -> XA (no conv phase)
  l1_kernel<<<(kNT + 15) / 16, 512, 0, stream>>>(PQ2, PS, cat_node_ids, CSN, CS0, OFF,
                                                 CURSOR, XA);
  // layer 2: gather from XA via compacted positive CSR, fused pool -> XG
  gconv_kernel<1><<<(kNT + 63) / 64, 512, 0, stream>>>(XA, XA, CSRS2, CS1C, OFF2, CURSOR2,
                                                       nullptr, conv_w + (size_t)kH * kD,
                                                       conv_b + kH, nullptr, XG, batch);

  final_kernel<<<2, 256, 0, stream>>>(XG, CNT, XNACC, CNTE, mlp_w, mlp_b, (float*)d_out);
}

// Round 22
// 370.831 us; speedup vs baseline: 1.1289x; 1.1195x over previous
//
#include <hip/hip_runtime.h>
#include <math.h>

namespace {
constexpr int kB = 16, kV = 30, kNV = 1501, kNE = 2001, kH = 128, kD = 128,
              kL = 2, kOut = 25, kNT = 100000, kE = 800000, kM = kB * kV;
constexpr int kNB = (kNT + 255) / 256;  // 391 scan blocks
constexpr int kKT = 47;                 // k-chunks of 32 (47*32 = 1504 >= 1501)
constexpr int kKP = kKT * 32;           // padded K = 1504
constexpr int kKSZ = 4;                 // split-K blocks for z (R19 proven config)
constexpr int kKCH = 12;                // k-chunks per split slice (4*12=48 >= 47)
constexpr int kNVZ = 1536;              // padded n-stride for z partials
constexpr int kMZ = 512;                // padded M = 16 b x 32 v
}

// PN[n] = node_emb[n]@lin_w^T + lin_b; PQ2[n] = relu(PN[n])@W1^T,
// PQ2[kNV+n] = relu(-PN[n])@W1^T; PS[n] = PN[n]@W1^T + b1.
__global__ void pn_kernel(const float* __restrict__ emb, const float* __restrict__ lw,
                          const float* __restrict__ lb, const float* __restrict__ cw,
                          const float* __restrict__ cb, float* __restrict__ pn,
                          float* __restrict__ pq2, float* __restrict__ ps) {
  int n = blockIdx.x, h = threadIdx.x;
  __shared__ float erow[kD];
  __shared__ float row[kD];
  erow[h] = emb[(size_t)n * kD + h];
  __syncthreads();
  float acc = lb[h];
#pragma unroll 8
  for (int d = 0; d < kD; d++) acc += erow[d] * lw[h * kD + d];
  pn[(size_t)n * kH + h] = acc;
  row[h] = acc;
  __syncthreads();
  float ap = 0.f, am = 0.f, aps = cb[h];
  const float* wr = cw + h * kD;
#pragma unroll 8
  for (int d = 0; d < kD; d++) {
    float r = row[d];
    float w = wr[d];
    ap = fmaf(fmaxf(r, 0.f), w, ap);
    am = fmaf(fmaxf(-r, 0.f), w, am);
    aps = fmaf(r, w, aps);
  }
  pq2[(size_t)n * kH + h] = ap;
  pq2[(size_t)(kNV + n) * kH + h] = am;
  ps[(size_t)n * kH + h] = aps;
}

// node branch partials
__global__ void xnode_kernel(const int* __restrict__ ehr, const float* __restrict__ pn,
                             float* __restrict__ xacc, int* __restrict__ cnte) {
  int b = blockIdx.x;
  int c = blockIdx.y;
  int h = threadIdx.x;
  int n0 = c * 128;
  __shared__ int flags[128];
  int gn = n0 + h;
  flags[h] = (gn < kNV) ? ehr[(size_t)b * kNV + gn] : 0;
  __syncthreads();
  float acc = 0.f;
  int cnt = 0;
  int n1 = min(n0 + 128, kNV);
  for (int n = n0; n < n1; ++n) {
    if (flags[n - n0]) {
      acc += pn[(size_t)n * kH + h];
      cnt++;
    }
  }
  atomicAdd(&xacc[b * kH + h], acc);
  if (h == 0) atomicAdd(&cnte[b], cnt);
}

// u[l][d] = sum_h wr_w[l][h]*lin_w[h][d] ; c[l] = wr_w[l].lin_b + wr_b[l]
__global__ void uc_kernel(const float* __restrict__ wrw, const float* __restrict__ wrb,
                          const float* __restrict__ lw, const float* __restrict__ lb,
                          float* __restrict__ uc) {
  int t = threadIdx.x;
  int l = t >> 7, d = t & 127;
  float s = 0.f;
  for (int h = 0; h < kH; h++) s += wrw[l * kH + h] * lw[h * kD + d];
  uc[t] = s;
  if (t < kL) {
    float c = wrb[t];
    for (int h = 0; h < kH; h++) c += wrw[t * kH + h] * lb[h];
    uc[256 + t] = c;
  }
}

// wrel[l][r] = sigmoid(edge_emb[r] . u[l] + c[l])
__global__ void wrel_kernel(const float* __restrict__ eemb, const float* __restrict__ uc,
                            float* __restrict__ wrel) {
  int idx = blockIdx.x * blockDim.x + threadIdx.x;
  if (idx >= kL * kNE) return;
  int l = idx / kNE, r = idx % kNE;
  float z = uc[256 + l];
  const float* u = uc + l * 128;
  const float* er = eemb + (size_t)r * kD;
  for (int d = 0; d < kD; d++) z += er[d] * u[d];
  wrel[idx] = 1.f / (1.f + expf(-z));
}

// beta[l][b*V+v] = tanh(vn[b,v,:].beta_w[l] + beta_b[l]) * exp(0.01*(V-v))
__global__ void beta_kernel(const int* __restrict__ vn, const float* __restrict__ bw,
                            const float* __restrict__ bb, float* __restrict__ beta) {
  int blk = blockIdx.x;
  int l = blk / kM, r = blk % kM;
  int v = r % kV;
  int lane = threadIdx.x;
  const int* row = vn + (size_t)r * kNV;
  const float* w = bw + (size_t)l * kNV;
  float s = 0.f;
  for (int k = lane; k < kNV; k += 64) s += (float)row[k] * w[k];
  for (int off = 32; off > 0; off >>= 1) s += __shfl_down(s, off, 64);
  if (lane == 0) {
    float lam = expf(0.01f * (float)(kV - v));
    beta[blk] = tanhf(s + bb[l]) * lam;
  }
}

// VNTALL[k][m] = (float)vn[b][v][k], m = b*32+v (512 cols), k padded to 1504.
__global__ void vnt_kernel(const int* __restrict__ vn, float* __restrict__ vnt) {
  int b = blockIdx.x, kt = blockIdx.y;
  int k0 = kt * 32;
  int tid = threadIdx.x;  // 256
  __shared__ float t[32][33];  // t[v][kk]
#pragma unroll
  for (int i = 0; i < 4; ++i) {
    int e = tid + i * 256;  // 1024 = 32v x 32k
    int v = e >> 5, kk = e & 31;
    int gk = k0 + kk;
    t[v][kk] = (v < kV && gk < kNV) ? (float)vn[(size_t)(b * kV + v) * kNV + gk] : 0.f;
  }
  __syncthreads();
  float* out = vnt + (size_t)k0 * kMZ + b * 32;
#pragma unroll
  for (int i = 0; i < 4; ++i) {
    int e = tid + i * 256;
    int kk = e >> 5, v = e & 31;
    out[(size_t)kk * kMZ + v] = t[v][kk];
  }
}

// Split-K partial z (R19 proven config): 64m x 128n tile, 4x8 per thread,
// grid (12, 8, kL*kKSZ=8) = 768 blocks.
__global__ void zpart_kernel(const float* __restrict__ vntall, const float* __restrict__ aw,
                             float* __restrict__ zp) {
  const int zidx = blockIdx.z;
  const int l = zidx / kKSZ, ks = zidx % kKSZ;
  const int mb = blockIdx.y * 64;
  const int nb = blockIdx.x * 128;
  const int tid = threadIdx.x;  // 256
  __shared__ float As[32 * 64];   // 8 KB [kk][m], k-major (no transpose needed)
  __shared__ float Bs[32 * 128];  // 16 KB [kk][n], XOR granule-swizzled
  const float* awl = aw + (size_t)l * kNV * kNV;
  const int tx = tid & 15;   // n pair-granule: cols tx*4 and 64+tx*4
  const int ty = tid >> 4;   // m granule: rows ty*4
  const int snn = tid >> 3;  // Bs staging n within 32-row group
  const int sk4 = (tid & 7) * 4;
  const int ct0 = ks * kKCH;
  const int ct1 = min(ct0 + kKCH, kKT);
  float acc[4][8] = {};
  for (int kt = ct0; kt < ct1; ++kt) {
    const int k0 = kt * 32;
    __syncthreads();
    // ---- stage As: 32k x 64m, plain float4 copies (both k-major) ----
#pragma unroll
    for (int i = 0; i < 2; ++i) {
      int e = tid + i * 256;  // 512 float4
      int kk = e >> 4, mq = (e & 15) * 4;
      *(float4*)&As[kk * 64 + mq] =
          *(const float4*)(vntall + (size_t)(k0 + kk) * kMZ + mb + mq);
    }
    // ---- stage Bs: 128n x 32k with XOR granule swizzle ----
    if (k0 + 32 <= kNV) {
#pragma unroll
      for (int i = 0; i < 4; ++i) {
        int nn = snn + 32 * i;
        int gn = nb + nn;
        float4 a = (gn < kNV) ? *(const float4*)(awl + (size_t)gn * kNV + k0 + sk4)
                              : float4{0.f, 0.f, 0.f, 0.f};
        float av[4] = {a.x, a.y, a.z, a.w};
#pragma unroll
        for (int j = 0; j < 4; ++j) {
          int kk = sk4 + j;
          int g = (nn >> 2) ^ (kk >> 2);
          Bs[kk * 128 + (g << 2) + (nn & 3)] = av[j];
        }
      }
    } else {
#pragma unroll
      for (int i = 0; i < 4; ++i) {
        int nn = snn + 32 * i;
        int gn = nb + nn;
#pragma unroll
        for (int j = 0; j < 4; ++j) {
          int kk = sk4 + j;
          int gk = k0 + kk;
          float v = (gn < kNV && gk < kNV) ? awl[(size_t)gn * kNV + gk] : 0.f;
          int g = (nn >> 2) ^ (kk >> 2);
          Bs[kk * 128 + (g << 2) + (nn & 3)] = v;
        }
      }
    }
    __syncthreads();
#pragma unroll 4
    for (int kk = 0; kk < 32; ++kk) {
      float4 a4 = *(const float4*)&As[kk * 64 + ty * 4];
      float4 b0 = *(const float4*)&Bs[kk * 128 + ((tx ^ (kk >> 2)) << 2)];
      float4 b1 = *(const float4*)&Bs[kk * 128 + (((tx + 16) ^ (kk >> 2)) << 2)];
      float am[4] = {a4.x, a4.y, a4.z, a4.w};
      float bn[8] = {b0.x, b0.y, b0.z, b0.w, b1.x, b1.y, b1.z, b1.w};
#pragma unroll
      for (int i2 = 0; i2 < 4; ++i2)
#pragma unroll
        for (int j2 = 0; j2 < 8; ++j2) acc[i2][j2] += am[i2] * bn[j2];
    }
  }
  float* zb = zp + (size_t)(ks * kL + l) * kMZ * kNVZ;
#pragma unroll
  for (int i2 = 0; i2 < 4; ++i2) {
    int m = mb + ty * 4 + i2;
    *(float4*)&zb[(size_t)m * kNVZ + nb + tx * 4] =
        float4{acc[i2][0], acc[i2][1], acc[i2][2], acc[i2][3]};
    *(float4*)&zb[(size_t)m * kNVZ + nb + 64 + tx * 4] =
        float4{acc[i2][4], acc[i2][5], acc[i2][6], acc[i2][7]};
  }
}

// attn[l][b][n] = sum_v softmax_v(sum_ks zp) * beta[l][b][v]
__global__ void zsm_kernel(const float* __restrict__ zp, const float* __restrict__ beta,
                           float* __restrict__ attn) {
  int idx = blockIdx.x * blockDim.x + threadIdx.x;
  if (idx >= kL * kB * kNV) return;
  int n = idx % kNV;
  int lb_ = idx / kNV;  // l*kB + b
  int l = lb_ / kB, b = lb_ % kB;
  const size_t PSTR = (size_t)kL * kMZ * kNVZ;  // partial stride
  const float* p = zp + ((size_t)l * kMZ + b * 32) * kNVZ + n;
  float zz[kV];
  float m = -1e30f;
#pragma unroll
  for (int v = 0; v < kV; ++v) {
    size_t o = (size_t)v * kNVZ;
    float s = p[o] + p[o + PSTR] + p[o + 2 * PSTR] + p[o + 3 * PSTR];
    zz[v] = s;
    m = fmaxf(m, s);
  }
  float s = 0.f, num = 0.f;
  const float* bet = beta + lb_ * kV;
#pragma unroll
  for (int v = 0; v < kV; ++v) {
    float e = expf(zz[v] - m);
    s += e;
    num += e * bet[v];
  }
  attn[idx] = num / s;
}

// ---- CSR build ----
__global__ void hist_kernel(const int* __restrict__ ei, const int* __restrict__ nid,
                            const int* __restrict__ batch, const float* __restrict__ attn,
                            int* __restrict__ deg, int* __restrict__ deg2) {
  int e = blockIdx.x * blockDim.x + threadIdx.x;
  if (e >= kE) return;
  int d = ei[kE + e];
  atomicAdd(&deg[d], 1);
  int s = ei[e];
  float a1 = attn[(size_t)kB * kNV + batch[s] * kNV + nid[s]];
  if (a1 > 0.f) atomicAdd(&deg2[d], 1);
}

// dual scans: process deg and deg2 in lockstep (halves launch count)
__global__ void scan1_dual(const int* __restrict__ deg, const int* __restrict__ deg2,
                           int* __restrict__ off, int* __restrict__ off2,
                           int* __restrict__ part, int* __restrict__ part2) {
  int t = threadIdx.x, i = blockIdx.x * 256 + t;
  int v1 = (i < kNT) ? deg[i] : 0;
  int v2 = (i < kNT) ? deg2[i] : 0;
  __shared__ int s1[256];
  __shared__ int s2[256];
  s1[t] = v1;
  s2[t] = v2;
  __syncthreads();
  for (int o = 1; o < 256; o <<= 1) {
    int x1 = (t >= o) ? s1[t - o] : 0;
    int x2 = (t >= o) ? s2[t - o] : 0;
    __syncthreads();
    s1[t] += x1;
    s2[t] += x2;
    __syncthreads();
  }
  if (i < kNT) {
    off[i] = s1[t] - v1;
    off2[i] = s2[t] - v2;
  }
  if (t == 255) {
    part[blockIdx.x] = s1[255];
    part2[blockIdx.x] = s2[255];
  }
}

__global__ void scan2_dual(int* __restrict__ part, int* __restrict__ part2) {
  int t = threadIdx.x;  // 512
  int v1 = (t < kNB) ? part[t] : 0;
  int v2 = (t < kNB) ? part2[t] : 0;
  __shared__ int s1[512];
  __shared__ int s2[512];
  s1[t] = v1;
  s2[t] = v2;
  __syncthreads();
  for (int o = 1; o < 512; o <<= 1) {
    int x1 = (t >= o) ? s1[t - o] : 0;
    int x2 = (t >= o) ? s2[t - o] : 0;
    __syncthreads();
    s1[t] += x1;
    s2[t] += x2;
    __syncthreads();
  }
  if (t < kNB) {
    part[t] = s1[t] - v1;
    part2[t] = s2[t] - v2;
  }
}

__global__ void scan3_dual(int* __restrict__ off, const int* __restrict__ part,
                           int* __restrict__ cursor, int* __restrict__ off2,
                           const int* __restrict__ part2, int* __restrict__ cursor2) {
  int i = blockIdx.x * 256 + threadIdx.x;
  if (i >= kNT) return;
  int o1 = off[i] + part[blockIdx.x];
  off[i] = o1;
  cursor[i] = o1;
  int o2 = off2[i] + part2[blockIdx.x];
  off2[i] = o2;
  cursor2[i] = o2;
}

// counts per batch segment: per-block LDS histogram, 16 global atomics/block
__global__ void cnt_kernel(const int* __restrict__ batch, int* __restrict__ cnt) {
  __shared__ int hist[kB];
  int t = threadIdx.x;
  if (t < kB) hist[t] = 0;
  __syncthreads();
  int i = blockIdx.x * blockDim.x + t;
  if (i < kNT) atomicAdd(&hist[batch[i]], 1);
  __syncthreads();
  if (t < kB && hist[t]) atomicAdd(&cnt[t], hist[t]);
}

// scatter: layer-1 CSR (csn sign-folded row, |cs0|w0) + compacted positive CSR
__global__ void scatter_kernel(const int* __restrict__ ei, const int* __restrict__ nid,
                               const int* __restrict__ eid, const int* __restrict__ batch,
                               const float* __restrict__ attn, const float* __restrict__ wrel,
                               int* __restrict__ cursor, int* __restrict__ csn,
                               float* __restrict__ cs0, int* __restrict__ cursor2,
                               int* __restrict__ csrc2, float* __restrict__ cs1c) {
  int e = blockIdx.x * blockDim.x + threadIdx.x;
  if (e >= kE) return;
  int s = ei[e], d = ei[kE + e];
  int b = batch[s], n = nid[s], r = eid[e];
  float a0 = attn[(size_t)b * kNV + n];
  float a1 = attn[(size_t)kB * kNV + b * kNV + n];
  float w0 = wrel[r], w1 = wrel[kNE + r];
  int pos = atomicAdd(&cursor[d], 1);
  csn[pos] = n + ((a0 > 0.f) ? 0 : kNV);
  cs0[pos] = fabsf(a0) * w0;
  if (a1 > 0.f) {
    int p2 = atomicAdd(&cursor2[d], 1);
    csrc2[p2] = s;
    cs1c[p2] = a1 * w1;
  }
}

#define GACC(A, V, C)                                  \
  A.x = fmaf(V.x, C, A.x); A.y = fmaf(V.y, C, A.y);    \
  A.z = fmaf(V.z, C, A.z); A.w = fmaf(V.w, C, A.w);

// Layer 1 in OUTPUT space: xa[node] = relu(PS[nid[node]] + sum_e cs0*PQ2[csn]).
__global__ void l1_kernel(const float* __restrict__ pq2, const float* __restrict__ psTab,
                          const int* __restrict__ nid, const int* __restrict__ csn,
                          const float* __restrict__ cs0, const int* __restrict__ off,
                          const int* __restrict__ endv, float* __restrict__ xa) {
  const int tid = threadIdx.x;  // 512
  const int lane = tid & 63;
  const int sub = lane >> 5, sl = lane & 31;
  const int hw = (tid >> 6) * 2 + sub;  // half-wave 0..15
  int node = blockIdx.x * 16 + hw;
  if (node >= kNT) return;
  const float4* x4 = (const float4*)pq2;
  float4 a0 = ((const float4*)psTab)[(size_t)nid[node] * 32 + sl];
  float4 a1 = {0.f, 0.f, 0.f, 0.f};
  float4 a2 = {0.f, 0.f, 0.f, 0.f};
  float4 a3 = {0.f, 0.f, 0.f, 0.f};
  int j0 = off[node], j1 = endv[node];
  for (int base = j0; base < j1; base += 32) {
    int n = j1 - base;
    if (n > 32) n = 32;
    int sidx = 0;
    float ssc = 0.f;
    if (sl < n) {
      sidx = csn[base + sl];
      ssc = cs0[base + sl];
    }
    int t = 0;
    for (; t + 8 <= n; t += 8) {
      int s0 = __shfl(sidx, sub * 32 + t + 0, 64);
      int s1 = __shfl(sidx, sub * 32 + t + 1, 64);
      int s2 = __shfl(sidx, sub * 32 + t + 2, 64);
      int s3 = __shfl(sidx, sub * 32 + t + 3, 64);
      int s4i = __shfl(sidx, sub * 32 + t + 4, 64);
      int s5 = __shfl(sidx, sub * 32 + t + 5, 64);
      int s6 = __shfl(sidx, sub * 32 + t + 6, 64);
      int s7 = __shfl(sidx, sub * 32 + t + 7, 64);
      float c0 = __shfl(ssc, sub * 32 + t + 0, 64);
      float c1 = __shfl(ssc, sub * 32 + t + 1, 64);
      float c2 = __shfl(ssc, sub * 32 + t + 2, 64);
      float c3 = __shfl(ssc, sub * 32 + t + 3, 64);
      float c4 = __shfl(ssc, sub * 32 + t + 4, 64);
      float c5 = __shfl(ssc, sub * 32 + t + 5, 64);
      float c6 = __shfl(ssc, sub * 32 + t + 6, 64);
      float c7 = __shfl(ssc, sub * 32 + t + 7, 64);
      float4 v0 = x4[(size_t)s0 * 32 + sl];
      float4 v1 = x4[(size_t)s1 * 32 + sl];
      float4 v2 = x4[(size_t)s2 * 32 + sl];
      float4 v3 = x4[(size_t)s3 * 32 + sl];
      float4 v4 = x4[(size_t)s4i * 32 + sl];
      float4 v5 = x4[(size_t)s5 * 32 + sl];
      float4 v6 = x4[(size_t)s6 * 32 + sl];
      float4 v7 = x4[(size_t)s7 * 32 + sl];
      GACC(a0, v0, c0);
      GACC(a1, v1, c1);
      GACC(a2, v2, c2);
      GACC(a3, v3, c3);
      GACC(a0, v4, c4);
      GACC(a1, v5, c5);
      GACC(a2, v6, c6);
      GACC(a3, v7, c7);
    }
    for (; t + 4 <= n; t += 4) {
      int s0 = __shfl(sidx, sub * 32 + t + 0, 64);
      int s1 = __shfl(sidx, sub * 32 + t + 1, 64);
      int s2 = __shfl(sidx, sub * 32 + t + 2, 64);
      int s3 = __shfl(sidx, sub * 32 + t + 3, 64);
      float c0 = __shfl(ssc, sub * 32 + t + 0, 64);
      float c1 = __shfl(ssc, sub * 32 + t + 1, 64);
      float c2 = __shfl(ssc, sub * 32 + t + 2, 64);
      float c3 = __shfl(ssc, sub * 32 + t + 3, 64);
      float4 v0 = x4[(size_t)s0 * 32 + sl];
      float4 v1 = x4[(size_t)s1 * 32 + sl];
      float4 v2 = x4[(size_t)s2 * 32 + sl];
      float4 v3 = x4[(size_t)s3 * 32 + sl];
      GACC(a0, v0, c0);
      GACC(a1, v1, c1);
      GACC(a2, v2, c2);
      GACC(a3, v3, c3);
    }
    for (; t < n; ++t) {
      int s = __shfl(sidx, sub * 32 + t, 64);
      float sc = __shfl(ssc, sub * 32 + t, 64);
      float4 xv = x4[(size_t)s * 32 + sl];
      GACC(a0, xv, sc);
    }
  }
  float4 o;
  o.x = fmaxf(a0.x + a1.x + a2.x + a3.x, 0.f);
  o.y = fmaxf(a0.y + a1.y + a2.y + a3.y, 0.f);
  o.z = fmaxf(a0.z + a1.z + a2.z + a3.z, 0.f);
  o.w = fmaxf(a0.w + a1.w + a2.w + a3.w, 0.f);
  ((float4*)xa)[(size_t)node * 32 + sl] = o;
}

// Fused gather+conv for layer 2 (pool path), 512 threads/block, pure-fma edges.
template <int POOL>
__global__ void gconv_kernel(const float* __restrict__ srcTab,
                             const float* __restrict__ selfTab,
                             const int* __restrict__ cidx, const float* __restrict__ cscal,
                             const int* __restrict__ off, const int* __restrict__ endv,
                             const int* __restrict__ selfIdx, const float* __restrict__ w,
                             const float* __restrict__ bias, float* __restrict__ xout,
                             float* __restrict__ xg, const int* __restrict__ batch) {
  const int nb = blockIdx.x * 64;
  const int tid = threadIdx.x;  // 512
  __shared__ float As[128 * 64];
  __shared__ float Ws[32 * 132];
  const int wv = tid >> 6;
  const int lane = tid & 63;
  const int sub = lane >> 5, sl = lane & 31;
  const int hw = wv * 2 + sub;
  const float4* x4 = (const float4*)srcTab;
  const float4* s4 = (const float4*)selfTab;
  for (int p = 0; p < 4; ++p) {
    int nl = p * 16 + hw;
    int node = nb + nl;
    if (node < kNT) {
      int selfRow = selfIdx ? selfIdx[node] : node;
      float4 a0 = s4[(size_t)selfRow * 32 + sl];
      float4 a1 = {0.f, 0.f, 0.f, 0.f};
      float4 a2 = {0.f, 0.f, 0.f, 0.f};
      float4 a3 = {0.f, 0.f, 0.f, 0.f};
      int j0 = off[node], j1 = endv[node];
      for (int base = j0; base < j1; base += 32) {
        int n = j1 - base;
        if (n > 32) n = 32;
        int sidx = 0;
        float ssc = 0.f;
        if (sl < n) {
          sidx = cidx[base + sl];
          ssc = cscal[base + sl];
        }
        int t = 0;
        for (; t + 8 <= n; t += 8) {
          int s0 = __shfl(sidx, sub * 32 + t + 0, 64);
          int s1 = __shfl(sidx, sub * 32 + t + 1, 64);
          int s2 = __shfl(sidx, sub * 32 + t + 2, 64);
          int s3 = __shfl(sidx, sub * 32 + t + 3, 64);
          int s4i = __shfl(sidx, sub * 32 + t + 4, 64);
          int s5 = __shfl(sidx, sub * 32 + t + 5, 64);
          int s6 = __shfl(sidx, sub * 32 + t + 6, 64);
          int s7 = __shfl(sidx, sub * 32 + t + 7, 64);
          float c0 = __shfl(ssc, sub * 32 + t + 0, 64);
          float c1 = __shfl(ssc, sub * 32 + t + 1, 64);
          float c2 = __shfl(ssc, sub * 32 + t + 2, 64);
          float c3 = __shfl(ssc, sub * 32 + t + 3, 64);
          float c4 = __shfl(ssc, sub * 32 + t + 4, 64);
          float c5 = __shfl(ssc, sub * 32 + t + 5, 64);
          float c6 = __shfl(ssc, sub * 32 + t + 6, 64);
          float c7 = __shfl(ssc, sub * 32 + t + 7, 64);
          float4 v0 = x4[(size_t)s0 * 32 + sl];
          float4 v1 = x4[(size_t)s1 * 32 + sl];
          float4 v2 = x4[(size_t)s2 * 32 + sl];
          float4 v3 = x4[(size_t)s3 * 32 + sl];
          float4 v4 = x4[(size_t)s4i * 32 + sl];
          float4 v5 = x4[(size_t)s5 * 32 + sl];
          float4 v6 = x4[(size_t)s6 * 32 + sl];
          float4 v7 = x4[(size_t)s7 * 32 + sl];
          GACC(a0, v0, c0);
          GACC(a1, v1, c1);
          GACC(a2, v2, c2);
          GACC(a3, v3, c3);
          GACC(a0, v4, c4);
          GACC(a1, v5, c5);
          GACC(a2, v6, c6);
          GACC(a3, v7, c7);
        }
        for (; t + 4 <= n; t += 4) {
          int s0 = __shfl(sidx, sub * 32 + t + 0, 64);
          int s1 = __shfl(sidx, sub * 32 + t + 1, 64);
          int s2 = __shfl(sidx, sub * 32 + t + 2, 64);
          int s3 = __shfl(sidx, sub * 32 + t + 3, 64);
          float c0 = __shfl(ssc, sub * 32 + t + 0, 64);
          float c1 = __shfl(ssc, sub * 32 + t + 1, 64);
          float c2 = __shfl(ssc, sub * 32 + t + 2, 64);
          float c3 = __shfl(ssc, sub * 32 + t + 3, 64);
          float4 v0 = x4[(size_t)s0 * 32 + sl];
          float4 v1 = x4[(size_t)s1 * 32 + sl];
          float4 v2 = x4[(size_t)s2 * 32 + sl];
          float4 v3 = x4[(size_t)s3 * 32 + sl];
          GACC(a0, v0, c0);
          GACC(a1, v1, c1);
          GACC(a2, v2, c2);
          GACC(a3, v3, c3);
        }
        for (; t < n; ++t) {
          int s = __shfl(sidx, sub * 32 + t, 64);
          float sc = __shfl(ssc, sub * 32 + t, 64);
          float4 xv = x4[(size_t)s * 32 + sl];
          GACC(a0, xv, sc);
        }
      }
      float av[4] = {a0.x + a1.x + a2.x + a3.x, a0.y + a1.y + a2.y + a3.y,
                     a0.z + a1.z + a2.z + a3.z, a0.w + a1.w + a2.w + a3.w};
#pragma unroll
      for (int j = 0; j < 4; ++j) {
        int d = sl * 4 + j;
        int g = (nl >> 2) ^ (sl & 15);
        As[d * 64 + (g << 2) + (nl & 3)] = av[j];
      }
    }
  }
  __syncthreads();
  const int tx = tid & 31, ty = tid >> 5;
  const int n0 = tx * 4;
  float acc[4][4] = {};
  for (int kc = 0; kc < 4; ++kc) {
    if (kc) __syncthreads();
#pragma unroll
    for (int i = 0; i < 2; ++i) {
      int fi = tid + i * 512;
      int hh = fi >> 3, c4 = (fi & 7) * 4;
      float4 v = *(const float4*)(w + (size_t)hh * kD + kc * 32 + c4);
      Ws[(c4 + 0) * 132 + hh] = v.x;
      Ws[(c4 + 1) * 132 + hh] = v.y;
      Ws[(c4 + 2) * 132 + hh] = v.z;
      Ws[(c4 + 3) * 132 + hh] = v.w;
    }
    __syncthreads();
#pragma unroll
    for (int dd = 0; dd < 32; ++dd) {
      int d = kc * 32 + dd;
      float4 a = *(const float4*)&As[d * 64 + ((ty ^ ((d >> 2) & 15)) << 2)];
      float4 b0 = *(const float4*)&Ws[dd * 132 + n0];
      float am[4] = {a.x, a.y, a.z, a.w};
      float bn[4] = {b0.x, b0.y, b0.z, b0.w};
#pragma unroll
      for (int i2 = 0; i2 < 4; ++i2)
#pragma unroll
        for (int j2 = 0; j2 < 4; ++j2) acc[i2][j2] += am[i2] * bn[j2];
    }
  }
  float4 bv0 = *(const float4*)(bias + n0);
  float bb[4] = {bv0.x, bv0.y, bv0.z, bv0.w};
  if (POOL == 0) {
#pragma unroll
    for (int i2 = 0; i2 < 4; ++i2) {
      int r = nb + ty * 4 + i2;
      if (r < kNT) {
        float4 o0;
        o0.x = fmaxf(acc[i2][0] + bb[0], 0.f);
        o0.y = fmaxf(acc[i2][1] + bb[1], 0.f);
        o0.z = fmaxf(acc[i2][2] + bb[2], 0.f);
        o0.w = fmaxf(acc[i2][3] + bb[3], 0.f);
        *(float4*)(xout + (size_t)r * kH + n0) = o0;
      }
    }
  } else {
    int rlast = min(nb + 63, kNT - 1);
    int b0 = batch[nb], b1 = batch[rlast];
    if (b0 == b1) {
      float p[4] = {};
#pragma unroll
      for (int i2 = 0; i2 < 4; ++i2) {
        int r = nb + ty * 4 + i2;
        if (r < kNT) {
#pragma unroll
          for (int j2 = 0; j2 < 4; ++j2) p[j2] += fmaxf(acc[i2][j2] + bb[j2], 0.f);
        }
      }
      __syncthreads();
      float* Ls = Ws;  // [16][132]
#pragma unroll
      for (int j2 = 0; j2 < 4; ++j2) Ls[ty * 132 + n0 + j2] = p[j2];
      __syncthreads();
      if (tid < 128) {
        float s = 0.f;
#pragma unroll
        for (int r2 = 0; r2 < 16; ++r2) s += Ls[r2 * 132 + tid];
        atomicAdd(&xg[b0 * kH + tid], s);
      }
    } else {
#pragma unroll
      for (int i2 = 0; i2 < 4; ++i2) {
        int r = nb + ty * 4 + i2;
        if (r < kNT) {
          int br = batch[r];
#pragma unroll
          for (int j2 = 0; j2 < 4; ++j2)
            atomicAdd(&xg[br * kH + n0 + j2], fmaxf(acc[i2][j2] + bb[j2], 0.f));
        }
      }
    }
  }
}

// out[b][o] = concat(xg[b]/cnt[b], xacc[b]/cnte[b]) . mlp_w[o] + mlp_b[o]
__global__ void final_kernel(const float* __restrict__ xg, const int* __restrict__ cnt,
                             const float* __restrict__ xacc, const int* __restrict__ cnte,
                             const float* __restrict__ mw, const float* __restrict__ mb,
                             float* __restrict__ out) {
  int idx = blockIdx.x * blockDim.x + threadIdx.x;
  if (idx >= kB * kOut) return;
  int b = idx / kOut, o = idx % kOut;
  float invg = 1.f / (float)cnt[b];
  float invn = 1.f / (float)cnte[b];
  float acc = mb[o];
  const float* w = mw + (size_t)o * (2 * kH);
  for (int h = 0; h < kH; h++) acc += xg[b * kH + h] * invg * w[h];
  for (int h = 0; h < kH; h++) acc += xacc[b * kH + h] * invn * w[kH + h];
  out[idx] = acc;
}

extern "C" void kernel_launch(void* const* d_in, const int* in_sizes, int n_in,
                              void* d_out, int out_size, void* d_ws, size_t ws_size,
                              hipStream_t stream) {
  const float* node_emb = (const float*)d_in[0];
  const float* edge_emb = (const float*)d_in[1];
  const float* lin_w = (const float*)d_in[2];
  const float* lin_b = (const float*)d_in[3];
  const float* alpha_w = (const float*)d_in[4];
  const float* alpha_b = (const float*)d_in[5];
  const float* beta_w = (const float*)d_in[6];
  const float* beta_b = (const float*)d_in[7];
  const float* wr_w = (const float*)d_in[8];
  const float* wr_b = (const float*)d_in[9];
  const float* conv_w = (const float*)d_in[10];
  const float* conv_b = (const float*)d_in[11];
  const float* mlp_w = (const float*)d_in[12];
  const float* mlp_b = (const float*)d_in[13];
  const int* visit_node = (const int*)d_in[14];
  const int* ehr_nodes = (const int*)d_in[15];
  const int* cat_node_ids = (const int*)d_in[16];
  const int* cat_edge_ids = (const int*)d_in[17];
  const int* edge_index = (const int*)d_in[18];
  const int* batch = (const int*)d_in[19];

  char* ws = (char*)d_ws;
  float* XA = (float*)(ws);                           // 51,200,000
  float* XB = (float*)(ws + 51200000);                // scratch region
  float* PN = XB;                                     // 768,512 at XB base
  float* VNT = (float*)(ws + 51200000 + 1048576);     // 3,080,192 (ends 55,328,768)
  float* ZP = (float*)(ws + 56000000);                // 25,165,824 (ends 81,165,824)
  int* CSN = (int*)(ws + 56000000);                   // 3,200,000 (dead-ZP after zsm)
  int* CSRS2 = (int*)(ws + 59200000);                 // 3,200,000
  float* CS1C = (float*)(ws + 62400000);              // 3,200,000
  int* OFF2 = (int*)(ws + 65600000);                  // 400,004 (dead-ZP after zsm)
  float* PQ2 = (float*)(ws + 81200000);               // 1,537,024 (outside ZP span)
  float* PS = (float*)(ws + 82800000);                // 768,512
  float* ATTN = (float*)(ws + 102400000);             // 192,128
  float* BETA = (float*)(ws + 102592256);             // 3,840
  float* UC = (float*)(ws + 102596352);               // 1,032
  float* WREL = (float*)(ws + 102597632);             // 16,008
  int* OFF = (int*)(ws + 102613760);                  // 400,004
  int* CURSOR = (int*)(ws + 103014016);               // 400,000
  int* CURSOR2 = (int*)(ws + 103414016);              // 400,000 (contiguous w/ CURSOR)
  int* SPART = (int*)(ws + 103814016);                // 2,048
  int* SPART2 = (int*)(ws + 103816064);               // 2,048
  float* CS0 = (float*)(ws + 106616064);              // 3,200,000
  float* XG = (float*)(ws + 113016064);               // 8,192
  int* CNT = (int*)(ws + 113024256);                  // 64
  float* XNACC = (float*)(ws + 113024320);            // 8,192
  int* CNTE = (int*)(ws + 113032512);                 // 64

  pn_kernel<<<kNV, kH, 0, stream>>>(node_emb, lin_w, lin_b, conv_w, conv_b, PN, PQ2, PS);
  hipMemsetAsync(XG, 0, 16512, stream);
  xnode_kernel<<<dim3(kB, 12), kH, 0, stream>>>(ehr_nodes, PN, XNACC, CNTE);
  cnt_kernel<<<kNB, 256, 0, stream>>>(batch, CNT);
  uc_kernel<<<1, 256, 0, stream>>>(wr_w, wr_b, lin_w, lin_b, UC);
  wrel_kernel<<<(kL * kNE + 255) / 256, 256, 0, stream>>>(edge_emb, UC, WREL);
  beta_kernel<<<kL * kM, 64, 0, stream>>>(visit_node, beta_w, beta_b, BETA);
  vnt_kernel<<<dim3(kB, kKT), 256, 0, stream>>>(visit_node, VNT);
  zpart_kernel<<<dim3((kNV + 127) / 128, kMZ / 64, kL * kKSZ), 256, 0, stream>>>(VNT, alpha_w,
                                                                                 ZP);
  zsm_kernel<<<(kL * kB * kNV + 255) / 256, 256, 0, stream>>>(ZP, BETA, ATTN);

  hipMemsetAsync(CURSOR, 0, 800000, stream);  // CURSOR + CURSOR2 (contiguous)
  hist_kernel<<<(kE + 255) / 256, 256, 0, stream>>>(edge_index, cat_node_ids, batch, ATTN,
                                                    CURSOR, CURSOR2);
  scan1_dual<<<kNB, 256, 0, stream>>>(CURSOR, CURSOR2, OFF, OFF2, SPART, SPART2);
  scan2_dual<<<1, 512, 0, stream>>>(SPART, SPART2);
  scan3_dual<<<kNB, 256, 0, stream>>>(OFF, SPART, CURSOR, OFF2, SPART2, CURSOR2);
  scatter_kernel<<<(kE + 255) / 256, 256, 0, stream>>>(edge_index, cat_node_ids, cat_edge_ids,
                                                       batch, ATTN, WREL, CURSOR, CSN, CS0,
                                                       CURSOR2, CSRS2, CS1C);

  // layer 1: output-space gather from PQ2/PS tables -> XA (no conv phase)
  l1_kernel<<<(kNT + 15) / 16, 512, 0, stream>>>(PQ2, PS, cat_node_ids, CSN, CS0, OFF,
                                                 CURSOR, XA);
  // layer 2: gather from XA via compacted positive CSR, fused pool -> XG
  gconv_kernel<1><<<(kNT + 63) / 64, 512, 0, stream>>>(XA, XA, CSRS2, CS1C, OFF2, CURSOR2,
                                                       nullptr, conv_w + (size_t)kH * kD,
                                                       conv_b + kH, nullptr, XG, batch);

  final_kernel<<<2, 256, 0, stream>>>(XG, CNT, XNACC, CNTE, mlp_w, mlp_b, (float*)d_out);
}

// Round 23
// 352.165 us; speedup vs baseline: 1.1887x; 1.0530x over previous
//
#include <hip/hip_runtime.h>
#include <math.h>

namespace {
constexpr int kB = 16, kV = 30, kNV = 1501, kNE = 2001, kH = 128, kD = 128,
              kL = 2, kOut = 25, kNT = 100000, kE = 800000, kM = kB * kV;
constexpr int kNB = (kNT + 255) / 256;  // 391 scan blocks
constexpr int kKP = 1504;               // padded K (and padded N for aw planes)
constexpr int kKSZ = 4;                 // split-K slices for z
constexpr int kNVZ = 1536;              // padded n-stride for z partials
constexpr int kMZ = 512;                // padded M = 16 b x 32 v
}

typedef __attribute__((ext_vector_type(8))) short bfrag;   // 8 bf16
typedef __attribute__((ext_vector_type(4))) float ffrag;   // 4 f32

__device__ inline unsigned short f2bf(float x) {  // round-to-nearest-even bf16
  unsigned u = __float_as_uint(x);
  unsigned r = u + 0x7FFFu + ((u >> 16) & 1u);
  return (unsigned short)(r >> 16);
}
__device__ inline float bf2f(unsigned short h) {
  return __uint_as_float(((unsigned)h) << 16);
}

// PN[n] = node_emb[n]@lin_w^T + lin_b; PQ2[n] = relu(PN[n])@W1^T,
// PQ2[kNV+n] = relu(-PN[n])@W1^T; PS[n] = PN[n]@W1^T + b1.
__global__ void pn_kernel(const float* __restrict__ emb, const float* __restrict__ lw,
                          const float* __restrict__ lb, const float* __restrict__ cw,
                          const float* __restrict__ cb, float* __restrict__ pn,
                          float* __restrict__ pq2, float* __restrict__ ps) {
  int n = blockIdx.x, h = threadIdx.x;
  __shared__ float erow[kD];
  __shared__ float row[kD];
  erow[h] = emb[(size_t)n * kD + h];
  __syncthreads();
  float acc = lb[h];
#pragma unroll 8
  for (int d = 0; d < kD; d++) acc += erow[d] * lw[h * kD + d];
  pn[(size_t)n * kH + h] = acc;
  row[h] = acc;
  __syncthreads();
  float ap = 0.f, am = 0.f, aps = cb[h];
  const float* wr = cw + h * kD;
#pragma unroll 8
  for (int d = 0; d < kD; d++) {
    float r = row[d];
    float w = wr[d];
    ap = fmaf(fmaxf(r, 0.f), w, ap);
    am = fmaf(fmaxf(-r, 0.f), w, am);
    aps = fmaf(r, w, aps);
  }
  pq2[(size_t)n * kH + h] = ap;
  pq2[(size_t)(kNV + n) * kH + h] = am;
  ps[(size_t)n * kH + h] = aps;
}

// node branch partials
__global__ void xnode_kernel(const int* __restrict__ ehr, const float* __restrict__ pn,
                             float* __restrict__ xacc, int* __restrict__ cnte) {
  int b = blockIdx.x;
  int c = blockIdx.y;
  int h = threadIdx.x;
  int n0 = c * 128;
  __shared__ int flags[128];
  int gn = n0 + h;
  flags[h] = (gn < kNV) ? ehr[(size_t)b * kNV + gn] : 0;
  __syncthreads();
  float acc = 0.f;
  int cnt = 0;
  int n1 = min(n0 + 128, kNV);
  for (int n = n0; n < n1; ++n) {
    if (flags[n - n0]) {
      acc += pn[(size_t)n * kH + h];
      cnt++;
    }
  }
  atomicAdd(&xacc[b * kH + h], acc);
  if (h == 0) atomicAdd(&cnte[b], cnt);
}

// u[l][d] = sum_h wr_w[l][h]*lin_w[h][d] ; c[l] = wr_w[l].lin_b + wr_b[l]
__global__ void uc_kernel(const float* __restrict__ wrw, const float* __restrict__ wrb,
                          const float* __restrict__ lw, const float* __restrict__ lb,
                          float* __restrict__ uc) {
  int t = threadIdx.x;
  int l = t >> 7, d = t & 127;
  float s = 0.f;
  for (int h = 0; h < kH; h++) s += wrw[l * kH + h] * lw[h * kD + d];
  uc[t] = s;
  if (t < kL) {
    float c = wrb[t];
    for (int h = 0; h < kH; h++) c += wrw[t * kH + h] * lb[h];
    uc[256 + t] = c;
  }
}

// wrel[l][r] = sigmoid(edge_emb[r] . u[l] + c[l])
__global__ void wrel_kernel(const float* __restrict__ eemb, const float* __restrict__ uc,
                            float* __restrict__ wrel) {
  int idx = blockIdx.x * blockDim.x + threadIdx.x;
  if (idx >= kL * kNE) return;
  int l = idx / kNE, r = idx % kNE;
  float z = uc[256 + l];
  const float* u = uc + l * 128;
  const float* er = eemb + (size_t)r * kD;
  for (int d = 0; d < kD; d++) z += er[d] * u[d];
  wrel[idx] = 1.f / (1.f + expf(-z));
}

// beta[l][b*V+v] = tanh(vn[b,v,:].beta_w[l] + beta_b[l]) * exp(0.01*(V-v))
__global__ void beta_kernel(const int* __restrict__ vn, const float* __restrict__ bw,
                            const float* __restrict__ bb, float* __restrict__ beta) {
  int blk = blockIdx.x;
  int l = blk / kM, r = blk % kM;
  int v = r % kV;
  int lane = threadIdx.x;
  const int* row = vn + (size_t)r * kNV;
  const float* w = bw + (size_t)l * kNV;
  float s = 0.f;
  for (int k = lane; k < kNV; k += 64) s += (float)row[k] * w[k];
  for (int off = 32; off > 0; off >>= 1) s += __shfl_down(s, off, 64);
  if (lane == 0) {
    float lam = expf(0.01f * (float)(kV - v));
    beta[blk] = tanhf(s + bb[l]) * lam;
  }
}

// vnbf[m][k] = bf16(vn[b][v][k]) with m=b*32+v, zero-padded v>=30, k>=1501.
__global__ void vnbf_kernel(const int* __restrict__ vn, short* __restrict__ out) {
  int m = blockIdx.x;  // 0..511
  int b = m >> 5, v = m & 31;
  for (int k = threadIdx.x; k < kKP; k += 256) {
    int val = (v < kV && k < kNV) ? vn[((size_t)(b * kV + v)) * kNV + k] : 0;
    out[(size_t)m * kKP + k] = val ? (short)0x3F80 : (short)0;
  }
}

// Exact 3-way bf16 split of aw: awh[p][l][n][k], n,k zero-padded to 1504.
__global__ void awsplit_kernel(const float* __restrict__ aw, short* __restrict__ awh) {
  int n = blockIdx.x;  // 0..1503
  int l = blockIdx.y;  // 0..1
  const size_t pl = (size_t)kKP * kKP;
  size_t rowo = ((size_t)l * kKP + n) * kKP;
  for (int k = threadIdx.x; k < kKP; k += 256) {
    float x = (n < kNV && k < kNV) ? aw[((size_t)l * kNV + n) * kNV + k] : 0.f;
    unsigned short h1 = f2bf(x);
    float r1 = x - bf2f(h1);
    unsigned short h2 = f2bf(r1);
    float r2 = r1 - bf2f(h2);
    unsigned short h3 = f2bf(r2);
    awh[rowo + k] = (short)h1;
    awh[2 * pl + rowo + k] = (short)h2;
    awh[4 * pl + rowo + k] = (short)h3;
  }
}

// MFMA z-partials: zp[ks][l][m][n] = sum_{k in slice} vn[m][k]*aw[l][n][k]
// via exact bf16 3-plane split. Wave tile 64m x 32n, direct global frag loads.
// Grid (47 n-strips, 2 m-halves, kL*kKSZ=8), 256 threads = 4 waves.
__global__ void zmfma_kernel(const short* __restrict__ vnbf, const short* __restrict__ awh,
                             float* __restrict__ zp) {
  const int l = blockIdx.z >> 2, ks = blockIdx.z & 3;
  const int wv = threadIdx.x >> 6, lane = threadIdx.x & 63;
  const int m0 = (blockIdx.y * 4 + wv) * 64;
  const int n0 = blockIdx.x * 32;
  const int lrow = lane & 15;
  const int koff = (lane >> 4) * 8;
  const size_t pl = (size_t)kKP * kKP;
  const short* b0p = awh + (size_t)l * pl;           // plane h1
  const short* b1p = awh + (2 + (size_t)l) * 2 * pl / 2;  // careful below
  // plane bases: p stride = 2*pl (two layers per plane)
  const short* p0 = awh + ((size_t)0 * 2 + l) * pl;
  const short* p1 = awh + ((size_t)1 * 2 + l) * pl;
  const short* p2 = awh + ((size_t)2 * 2 + l) * pl;
  (void)b0p; (void)b1p;
  ffrag acc[4][2];
#pragma unroll
  for (int i = 0; i < 4; ++i)
#pragma unroll
    for (int j = 0; j < 2; ++j) acc[i][j] = ffrag{0.f, 0.f, 0.f, 0.f};
  const int ct0 = ks * 12;
  const int ct1 = min(ct0 + 12, 47);
  for (int kt = ct0; kt < ct1; ++kt) {
    const int k = kt * 32 + koff;
    bfrag a0 = *(const bfrag*)(vnbf + (size_t)(m0 + 0 * 16 + lrow) * kKP + k);
    bfrag a1 = *(const bfrag*)(vnbf + (size_t)(m0 + 1 * 16 + lrow) * kKP + k);
    bfrag a2 = *(const bfrag*)(vnbf + (size_t)(m0 + 2 * 16 + lrow) * kKP + k);
    bfrag a3 = *(const bfrag*)(vnbf + (size_t)(m0 + 3 * 16 + lrow) * kKP + k);
    {
      bfrag b0 = *(const bfrag*)(p0 + (size_t)(n0 + lrow) * kKP + k);
      bfrag b1 = *(const bfrag*)(p0 + (size_t)(n0 + 16 + lrow) * kKP + k);
      acc[0][0] = __builtin_amdgcn_mfma_f32_16x16x32_bf16(a0, b0, acc[0][0], 0, 0, 0);
      acc[1][0] = __builtin_amdgcn_mfma_f32_16x16x32_bf16(a1, b0, acc[1][0], 0, 0, 0);
      acc[2][0] = __builtin_amdgcn_mfma_f32_16x16x32_bf16(a2, b0, acc[2][0], 0, 0, 0);
      acc[3][0] = __builtin_amdgcn_mfma_f32_16x16x32_bf16(a3, b0, acc[3][0], 0, 0, 0);
      acc[0][1] = __builtin_amdgcn_mfma_f32_16x16x32_bf16(a0, b1, acc[0][1], 0, 0, 0);
      acc[1][1] = __builtin_amdgcn_mfma_f32_16x16x32_bf16(a1, b1, acc[1][1], 0, 0, 0);
      acc[2][1] = __builtin_amdgcn_mfma_f32_16x16x32_bf16(a2, b1, acc[2][1], 0, 0, 0);
      acc[3][1] = __builtin_amdgcn_mfma_f32_16x16x32_bf16(a3, b1, acc[3][1], 0, 0, 0);
    }
    {
      bfrag b0 = *(const bfrag*)(p1 + (size_t)(n0 + lrow) * kKP + k);
      bfrag b1 = *(const bfrag*)(p1 + (size_t)(n0 + 16 + lrow) * kKP + k);
      acc[0][0] = __builtin_amdgcn_mfma_f32_16x16x32_bf16(a0, b0, acc[0][0], 0, 0, 0);
      acc[1][0] = __builtin_amdgcn_mfma_f32_16x16x32_bf16(a1, b0, acc[1][0], 0, 0, 0);
      acc[2][0] = __builtin_amdgcn_mfma_f32_16x16x32_bf16(a2, b0, acc[2][0], 0, 0, 0);
      acc[3][0] = __builtin_amdgcn_mfma_f32_16x16x32_bf16(a3, b0, acc[3][0], 0, 0, 0);
      acc[0][1] = __builtin_amdgcn_mfma_f32_16x16x32_bf16(a0, b1, acc[0][1], 0, 0, 0);
      acc[1][1] = __builtin_amdgcn_mfma_f32_16x16x32_bf16(a1, b1, acc[1][1], 0, 0, 0);
      acc[2][1] = __builtin_amdgcn_mfma_f32_16x16x32_bf16(a2, b1, acc[2][1], 0, 0, 0);
      acc[3][1] = __builtin_amdgcn_mfma_f32_16x16x32_bf16(a3, b1, acc[3][1], 0, 0, 0);
    }
    {
      bfrag b0 = *(const bfrag*)(p2 + (size_t)(n0 + lrow) * kKP + k);
      bfrag b1 = *(const bfrag*)(p2 + (size_t)(n0 + 16 + lrow) * kKP + k);
      acc[0][0] = __builtin_amdgcn_mfma_f32_16x16x32_bf16(a0, b0, acc[0][0], 0, 0, 0);
      acc[1][0] = __builtin_amdgcn_mfma_f32_16x16x32_bf16(a1, b0, acc[1][0], 0, 0, 0);
      acc[2][0] = __builtin_amdgcn_mfma_f32_16x16x32_bf16(a2, b0, acc[2][0], 0, 0, 0);
      acc[3][0] = __builtin_amdgcn_mfma_f32_16x16x32_bf16(a3, b0, acc[3][0], 0, 0, 0);
      acc[0][1] = __builtin_amdgcn_mfma_f32_16x16x32_bf16(a0, b1, acc[0][1], 0, 0, 0);
      acc[1][1] = __builtin_amdgcn_mfma_f32_16x16x32_bf16(a1, b1, acc[1][1], 0, 0, 0);
      acc[2][1] = __builtin_amdgcn_mfma_f32_16x16x32_bf16(a2, b1, acc[2][1], 0, 0, 0);
      acc[3][1] = __builtin_amdgcn_mfma_f32_16x16x32_bf16(a3, b1, acc[3][1], 0, 0, 0);
    }
  }
  // epilogue: C/D mapping col = lane&15, row = (lane>>4)*4 + reg (guide-verified)
  const int drow0 = (lane >> 4) * 4;
  float* zb = zp + (size_t)(ks * kL + l) * kMZ * kNVZ;
#pragma unroll
  for (int i = 0; i < 4; ++i) {
    int mrow = m0 + i * 16 + drow0;
#pragma unroll
    for (int j = 0; j < 2; ++j) {
      int ncol = n0 + j * 16 + lrow;
#pragma unroll
      for (int r = 0; r < 4; ++r) zb[(size_t)(mrow + r) * kNVZ + ncol] = acc[i][j][r];
    }
  }
}

// attn[l][b][n] = sum_v softmax_v(sum_ks zp) * beta[l][b][v]
__global__ void zsm_kernel(const float* __restrict__ zp, const float* __restrict__ beta,
                           float* __restrict__ attn) {
  int idx = blockIdx.x * blockDim.x + threadIdx.x;
  if (idx >= kL * kB * kNV) return;
  int n = idx % kNV;
  int lb_ = idx / kNV;  // l*kB + b
  int l = lb_ / kB, b = lb_ % kB;
  const size_t PSTR = (size_t)kL * kMZ * kNVZ;  // partial stride
  const float* p = zp + ((size_t)l * kMZ + b * 32) * kNVZ + n;
  float zz[kV];
  float m = -1e30f;
#pragma unroll
  for (int v = 0; v < kV; ++v) {
    size_t o = (size_t)v * kNVZ;
    float s = p[o] + p[o + PSTR] + p[o + 2 * PSTR] + p[o + 3 * PSTR];
    zz[v] = s;
    m = fmaxf(m, s);
  }
  float s = 0.f, num = 0.f;
  const float* bet = beta + lb_ * kV;
#pragma unroll
  for (int v = 0; v < kV; ++v) {
    float e = expf(zz[v] - m);
    s += e;
    num += e * bet[v];
  }
  attn[idx] = num / s;
}

// ---- CSR build ----
__global__ void hist_kernel(const int* __restrict__ ei, const int* __restrict__ nid,
                            const int* __restrict__ batch, const float* __restrict__ attn,
                            int* __restrict__ deg, int* __restrict__ deg2) {
  int e = blockIdx.x * blockDim.x + threadIdx.x;
  if (e >= kE) return;
  int d = ei[kE + e];
  atomicAdd(&deg[d], 1);
  int s = ei[e];
  float a1 = attn[(size_t)kB * kNV + batch[s] * kNV + nid[s]];
  if (a1 > 0.f) atomicAdd(&deg2[d], 1);
}

// dual scans: process deg and deg2 in lockstep (halves launch count)
__global__ void scan1_dual(const int* __restrict__ deg, const int* __restrict__ deg2,
                           int* __restrict__ off, int* __restrict__ off2,
                           int* __restrict__ part, int* __restrict__ part2) {
  int t = threadIdx.x, i = blockIdx.x * 256 + t;
  int v1 = (i < kNT) ? deg[i] : 0;
  int v2 = (i < kNT) ? deg2[i] : 0;
  __shared__ int s1[256];
  __shared__ int s2[256];
  s1[t] = v1;
  s2[t] = v2;
  __syncthreads();
  for (int o = 1; o < 256; o <<= 1) {
    int x1 = (t >= o) ? s1[t - o] : 0;
    int x2 = (t >= o) ? s2[t - o] : 0;
    __syncthreads();
    s1[t] += x1;
    s2[t] += x2;
    __syncthreads();
  }
  if (i < kNT) {
    off[i] = s1[t] - v1;
    off2[i] = s2[t] - v2;
  }
  if (t == 255) {
    part[blockIdx.x] = s1[255];
    part2[blockIdx.x] = s2[255];
  }
}

__global__ void scan2_dual(int* __restrict__ part, int* __restrict__ part2) {
  int t = threadIdx.x;  // 512
  int v1 = (t < kNB) ? part[t] : 0;
  int v2 = (t < kNB) ? part2[t] : 0;
  __shared__ int s1[512];
  __shared__ int s2[512];
  s1[t] = v1;
  s2[t] = v2;
  __syncthreads();
  for (int o = 1; o < 512; o <<= 1) {
    int x1 = (t >= o) ? s1[t - o] : 0;
    int x2 = (t >= o) ? s2[t - o] : 0;
    __syncthreads();
    s1[t] += x1;
    s2[t] += x2;
    __syncthreads();
  }
  if (t < kNB) {
    part[t] = s1[t] - v1;
    part2[t] = s2[t] - v2;
  }
}

__global__ void scan3_dual(int* __restrict__ off, const int* __restrict__ part,
                           int* __restrict__ cursor, int* __restrict__ off2,
                           const int* __restrict__ part2, int* __restrict__ cursor2) {
  int i = blockIdx.x * 256 + threadIdx.x;
  if (i >= kNT) return;
  int o1 = off[i] + part[blockIdx.x];
  off[i] = o1;
  cursor[i] = o1;
  int o2 = off2[i] + part2[blockIdx.x];
  off2[i] = o2;
  cursor2[i] = o2;
}

// counts per batch segment: per-block LDS histogram, 16 global atomics/block
__global__ void cnt_kernel(const int* __restrict__ batch, int* __restrict__ cnt) {
  __shared__ int hist[kB];
  int t = threadIdx.x;
  if (t < kB) hist[t] = 0;
  __syncthreads();
  int i = blockIdx.x * blockDim.x + t;
  if (i < kNT) atomicAdd(&hist[batch[i]], 1);
  __syncthreads();
  if (t < kB && hist[t]) atomicAdd(&cnt[t], hist[t]);
}

// scatter: layer-1 CSR (csn sign-folded row, |cs0|w0) + compacted positive CSR
__global__ void scatter_kernel(const int* __restrict__ ei, const int* __restrict__ nid,
                               const int* __restrict__ eid, const int* __restrict__ batch,
                               const float* __restrict__ attn, const float* __restrict__ wrel,
                               int* __restrict__ cursor, int* __restrict__ csn,
                               float* __restrict__ cs0, int* __restrict__ cursor2,
                               int* __restrict__ csrc2, float* __restrict__ cs1c) {
  int e = blockIdx.x * blockDim.x + threadIdx.x;
  if (e >= kE) return;
  int s = ei[e], d = ei[kE + e];
  int b = batch[s], n = nid[s], r = eid[e];
  float a0 = attn[(size_t)b * kNV + n];
  float a1 = attn[(size_t)kB * kNV + b * kNV + n];
  float w0 = wrel[r], w1 = wrel[kNE + r];
  int pos = atomicAdd(&cursor[d], 1);
  csn[pos] = n + ((a0 > 0.f) ? 0 : kNV);
  cs0[pos] = fabsf(a0) * w0;
  if (a1 > 0.f) {
    int p2 = atomicAdd(&cursor2[d], 1);
    csrc2[p2] = s;
    cs1c[p2] = a1 * w1;
  }
}

#define GACC(A, V, C)                                  \
  A.x = fmaf(V.x, C, A.x); A.y = fmaf(V.y, C, A.y);    \
  A.z = fmaf(V.z, C, A.z); A.w = fmaf(V.w, C, A.w);

// Layer 1 in OUTPUT space: xa[node] = relu(PS[nid[node]] + sum_e cs0*PQ2[csn]).
__global__ void l1_kernel(const float* __restrict__ pq2, const float* __restrict__ psTab,
                          const int* __restrict__ nid, const int* __restrict__ csn,
                          const float* __restrict__ cs0, const int* __restrict__ off,
                          const int* __restrict__ endv, float* __restrict__ xa) {
  const int tid = threadIdx.x;  // 512
  const int lane = tid & 63;
  const int sub = lane >> 5, sl = lane & 31;
  const int hw = (tid >> 6) * 2 + sub;  // half-wave 0..15
  int node = blockIdx.x * 16 + hw;
  if (node >= kNT) return;
  const float4* x4 = (const float4*)pq2;
  float4 a0 = ((const float4*)psTab)[(size_t)nid[node] * 32 + sl];
  float4 a1 = {0.f, 0.f, 0.f, 0.f};
  float4 a2 = {0.f, 0.f, 0.f, 0.f};
  float4 a3 = {0.f, 0.f, 0.f, 0.f};
  int j0 = off[node], j1 = endv[node];
  for (int base = j0; base < j1; base += 32) {
    int n = j1 - base;
    if (n > 32) n = 32;
    int sidx = 0;
    float ssc = 0.f;
    if (sl < n) {
      sidx = csn[base + sl];
      ssc = cs0[base + sl];
    }
    int t = 0;
    for (; t + 8 <= n; t += 8) {
      int s0 = __shfl(sidx, sub * 32 + t + 0, 64);
      int s1 = __shfl(sidx, sub * 32 + t + 1, 64);
      int s2 = __shfl(sidx, sub * 32 + t + 2, 64);
      int s3 = __shfl(sidx, sub * 32 + t + 3, 64);
      int s4i = __shfl(sidx, sub * 32 + t + 4, 64);
      int s5 = __shfl(sidx, sub * 32 + t + 5, 64);
      int s6 = __shfl(sidx, sub * 32 + t + 6, 64);
      int s7 = __shfl(sidx, sub * 32 + t + 7, 64);
      float c0 = __shfl(ssc, sub * 32 + t + 0, 64);
      float c1 = __shfl(ssc, sub * 32 + t + 1, 64);
      float c2 = __shfl(ssc, sub * 32 + t + 2, 64);
      float c3 = __shfl(ssc, sub * 32 + t + 3, 64);
      float c4 = __shfl(ssc, sub * 32 + t + 4, 64);
      float c5 = __shfl(ssc, sub * 32 + t + 5, 64);
      float c6 = __shfl(ssc, sub * 32 + t + 6, 64);
      float c7 = __shfl(ssc, sub * 32 + t + 7, 64);
      float4 v0 = x4[(size_t)s0 * 32 + sl];
      float4 v1 = x4[(size_t)s1 * 32 + sl];
      float4 v2 = x4[(size_t)s2 * 32 + sl];
      float4 v3 = x4[(size_t)s3 * 32 + sl];
      float4 v4 = x4[(size_t)s4i * 32 + sl];
      float4 v5 = x4[(size_t)s5 * 32 + sl];
      float4 v6 = x4[(size_t)s6 * 32 + sl];
      float4 v7 = x4[(size_t)s7 * 32 + sl];
      GACC(a0, v0, c0);
      GACC(a1, v1, c1);
      GACC(a2, v2, c2);
      GACC(a3, v3, c3);
      GACC(a0, v4, c4);
      GACC(a1, v5, c5);
      GACC(a2, v6, c6);
      GACC(a3, v7, c7);
    }
    for (; t + 4 <= n; t += 4) {
      int s0 = __shfl(sidx, sub * 32 + t + 0, 64);
      int s1 = __shfl(sidx, sub * 32 + t + 1, 64);
      int s2 = __shfl(sidx, sub * 32 + t + 2, 64);
      int s3 = __shfl(sidx, sub * 32 + t + 3, 64);
      float c0 = __shfl(ssc, sub * 32 + t + 0, 64);
      float c1 = __shfl(ssc, sub * 32 + t + 1, 64);
      float c2 = __shfl(ssc, sub * 32 + t + 2, 64);
      float c3 = __shfl(ssc, sub * 32 + t + 3, 64);
      float4 v0 = x4[(size_t)s0 * 32 + sl];
      float4 v1 = x4[(size_t)s1 * 32 + sl];
      float4 v2 = x4[(size_t)s2 * 32 + sl];
      float4 v3 = x4[(size_t)s3 * 32 + sl];
      GACC(a0, v0, c0);
      GACC(a1, v1, c1);
      GACC(a2, v2, c2);
      GACC(a3, v3, c3);
    }
    for (; t < n; ++t) {
      int s = __shfl(sidx, sub * 32 + t, 64);
      float sc = __shfl(ssc, sub * 32 + t, 64);
      float4 xv = x4[(size_t)s * 32 + sl];
      GACC(a0, xv, sc);
    }
  }
  float4 o;
  o.x = fmaxf(a0.x + a1.x + a2.x + a3.x, 0.f);
  o.y = fmaxf(a0.y + a1.y + a2.y + a3.y, 0.f);
  o.z = fmaxf(a0.z + a1.z + a2.z + a3.z, 0.f);
  o.w = fmaxf(a0.w + a1.w + a2.w + a3.w, 0.f);
  ((float4*)xa)[(size_t)node * 32 + sl] = o;
}

// Fused gather+conv for layer 2 (pool path), 512 threads/block, pure-fma edges.
template <int POOL>
__global__ void gconv_kernel(const float* __restrict__ srcTab,
                             const float* __restrict__ selfTab,
                             const int* __restrict__ cidx, const float* __restrict__ cscal,
                             const int* __restrict__ off, const int* __restrict__ endv,
                             const int* __restrict__ selfIdx, const float* __restrict__ w,
                             const float* __restrict__ bias, float* __restrict__ xout,
                             float* __restrict__ xg, const int* __restrict__ batch) {
  const int nb = blockIdx.x * 64;
  const int tid = threadIdx.x;  // 512
  __shared__ float As[128 * 64];
  __shared__ float Ws[32 * 132];
  const int wv = tid >> 6;
  const int lane = tid & 63;
  const int sub = lane >> 5, sl = lane & 31;
  const int hw = wv * 2 + sub;
  const float4* x4 = (const float4*)srcTab;
  const float4* s4 = (const float4*)selfTab;
  for (int p = 0; p < 4; ++p) {
    int nl = p * 16 + hw;
    int node = nb + nl;
    if (node < kNT) {
      int selfRow = selfIdx ? selfIdx[node] : node;
      float4 a0 = s4[(size_t)selfRow * 32 + sl];
      float4 a1 = {0.f, 0.f, 0.f, 0.f};
      float4 a2 = {0.f, 0.f, 0.f, 0.f};
      float4 a3 = {0.f, 0.f, 0.f, 0.f};
      int j0 = off[node], j1 = endv[node];
      for (int base = j0; base < j1; base += 32) {
        int n = j1 - base;
        if (n > 32) n = 32;
        int sidx = 0;
        float ssc = 0.f;
        if (sl < n) {
          sidx = cidx[base + sl];
          ssc = cscal[base + sl];
        }
        int t = 0;
        for (; t + 8 <= n; t += 8) {
          int s0 = __shfl(sidx, sub * 32 + t + 0, 64);
          int s1 = __shfl(sidx, sub * 32 + t + 1, 64);
          int s2 = __shfl(sidx, sub * 32 + t + 2, 64);
          int s3 = __shfl(sidx, sub * 32 + t + 3, 64);
          int s4i = __shfl(sidx, sub * 32 + t + 4, 64);
          int s5 = __shfl(sidx, sub * 32 + t + 5, 64);
          int s6 = __shfl(sidx, sub * 32 + t + 6, 64);
          int s7 = __shfl(sidx, sub * 32 + t + 7, 64);
          float c0 = __shfl(ssc, sub * 32 + t + 0, 64);
          float c1 = __shfl(ssc, sub * 32 + t + 1, 64);
          float c2 = __shfl(ssc, sub * 32 + t + 2, 64);
          float c3 = __shfl(ssc, sub * 32 + t + 3, 64);
          float c4 = __shfl(ssc, sub * 32 + t + 4, 64);
          float c5 = __shfl(ssc, sub * 32 + t + 5, 64);
          float c6 = __shfl(ssc, sub * 32 + t + 6, 64);
          float c7 = __shfl(ssc, sub * 32 + t + 7, 64);
          float4 v0 = x4[(size_t)s0 * 32 + sl];
          float4 v1 = x4[(size_t)s1 * 32 + sl];
          float4 v2 = x4[(size_t)s2 * 32 + sl];
          float4 v3 = x4[(size_t)s3 * 32 + sl];
          float4 v4 = x4[(size_t)s4i * 32 + sl];
          float4 v5 = x4[(size_t)s5 * 32 + sl];
          float4 v6 = x4[(size_t)s6 * 32 + sl];
          float4 v7 = x4[(size_t)s7 * 32 + sl];
          GACC(a0, v0, c0);
          GACC(a1, v1, c1);
          GACC(a2, v2, c2);
          GACC(a3, v3, c3);
          GACC(a0, v4, c4);
          GACC(a1, v5, c5);
          GACC(a2, v6, c6);
          GACC(a3, v7, c7);
        }
        for (; t + 4 <= n; t += 4) {
          int s0 = __shfl(sidx, sub * 32 + t + 0, 64);
          int s1 = __shfl(sidx, sub * 32 + t + 1, 64);
          int s2 = __shfl(sidx, sub * 32 + t + 2, 64);
          int s3 = __shfl(sidx, sub * 32 + t + 3, 64);
          float c0 = __shfl(ssc, sub * 32 + t + 0, 64);
          float c1 = __shfl(ssc, sub * 32 + t + 1, 64);
          float c2 = __shfl(ssc, sub * 32 + t + 2, 64);
          float c3 = __shfl(ssc, sub * 32 + t + 3, 64);
          float4 v0 = x4[(size_t)s0 * 32 + sl];
          float4 v1 = x4[(size_t)s1 * 32 + sl];
          float4 v2 = x4[(size_t)s2 * 32 + sl];
          float4 v3 = x4[(size_t)s3 * 32 + sl];
          GACC(a0, v0, c0);
          GACC(a1, v1, c1);
          GACC(a2, v2, c2);
          GACC(a3, v3, c3);
        }
        for (; t < n; ++t) {
          int s = __shfl(sidx, sub * 32 + t, 64);
          float sc = __shfl(ssc, sub * 32 + t, 64);
          float4 xv = x4[(size_t)s * 32 + sl];
          GACC(a0, xv, sc);
        }
      }
      float av[4] = {a0.x + a1.x + a2.x + a3.x, a0.y + a1.y + a2.y + a3.y,
                     a0.z + a1.z + a2.z + a3.z, a0.w + a1.w + a2.w + a3.w};
#pragma unroll
      for (int j = 0; j < 4; ++j) {
        int d = sl * 4 + j;
        int g = (nl >> 2) ^ (sl & 15);
        As[d * 64 + (g << 2) + (nl & 3)] = av[j];
      }
    }
  }
  __syncthreads();
  const int tx = tid & 31, ty = tid >> 5;
  const int n0 = tx * 4;
  float acc[4][4] = {};
  for (int kc = 0; kc < 4; ++kc) {
    if (kc) __syncthreads();
#pragma unroll
    for (int i = 0; i < 2; ++i) {
      int fi = tid + i * 512;
      int hh = fi >> 3, c4 = (fi & 7) * 4;
      float4 v = *(const float4*)(w + (size_t)hh * kD + kc * 32 + c4);
      Ws[(c4 + 0) * 132 + hh] = v.x;
      Ws[(c4 + 1) * 132 + hh] = v.y;
      Ws[(c4 + 2) * 132 + hh] = v.z;
      Ws[(c4 + 3) * 132 + hh] = v.w;
    }
    __syncthreads();
#pragma unroll
    for (int dd = 0; dd < 32; ++dd) {
      int d = kc * 32 + dd;
      float4 a = *(const float4*)&As[d * 64 + ((ty ^ ((d >> 2) & 15)) << 2)];
      float4 b0 = *(const float4*)&Ws[dd * 132 + n0];
      float am[4] = {a.x, a.y, a.z, a.w};
      float bn[4] = {b0.x, b0.y, b0.z, b0.w};
#pragma unroll
      for (int i2 = 0; i2 < 4; ++i2)
#pragma unroll
        for (int j2 = 0; j2 < 4; ++j2) acc[i2][j2] += am[i2] * bn[j2];
    }
  }
  float4 bv0 = *(const float4*)(bias + n0);
  float bb[4] = {bv0.x, bv0.y, bv0.z, bv0.w};
  if (POOL == 0) {
#pragma unroll
    for (int i2 = 0; i2 < 4; ++i2) {
      int r = nb + ty * 4 + i2;
      if (r < kNT) {
        float4 o0;
        o0.x = fmaxf(acc[i2][0] + bb[0], 0.f);
        o0.y = fmaxf(acc[i2][1] + bb[1], 0.f);
        o0.z = fmaxf(acc[i2][2] + bb[2], 0.f);
        o0.w = fmaxf(acc[i2][3] + bb[3], 0.f);
        *(float4*)(xout + (size_t)r * kH + n0) = o0;
      }
    }
  } else {
    int rlast = min(nb + 63, kNT - 1);
    int b0 = batch[nb], b1 = batch[rlast];
    if (b0 == b1) {
      float p[4] = {};
#pragma unroll
      for (int i2 = 0; i2 < 4; ++i2) {
        int r = nb + ty * 4 + i2;
        if (r < kNT) {
#pragma unroll
          for (int j2 = 0; j2 < 4; ++j2) p[j2] += fmaxf(acc[i2][j2] + bb[j2], 0.f);
        }
      }
      __syncthreads();
      float* Ls = Ws;  // [16][132]
#pragma unroll
      for (int j2 = 0; j2 < 4; ++j2) Ls[ty * 132 + n0 + j2] = p[j2];
      __syncthreads();
      if (tid < 128) {
        float s = 0.f;
#pragma unroll
        for (int r2 = 0; r2 < 16; ++r2) s += Ls[r2 * 132 + tid];
        atomicAdd(&xg[b0 * kH + tid], s);
      }
    } else {
#pragma unroll
      for (int i2 = 0; i2 < 4; ++i2) {
        int r = nb + ty * 4 + i2;
        if (r < kNT) {
          int br = batch[r];
#pragma unroll
          for (int j2 = 0; j2 < 4; ++j2)
            atomicAdd(&xg[br * kH + n0 + j2], fmaxf(acc[i2][j2] + bb[j2], 0.f));
        }
      }
    }
  }
}

// out[b][o] = concat(xg[b]/cnt[b], xacc[b]/cnte[b]) . mlp_w[o] + mlp_b[o]
__global__ void final_kernel(const float* __restrict__ xg, const int* __restrict__ cnt,
                             const float* __restrict__ xacc, const int* __restrict__ cnte,
                             const float* __restrict__ mw, const float* __restrict__ mb,
                             float* __restrict__ out) {
  int idx = blockIdx.x * blockDim.x + threadIdx.x;
  if (idx >= kB * kOut) return;
  int b = idx / kOut, o = idx % kOut;
  float invg = 1.f / (float)cnt[b];
  float invn = 1.f / (float)cnte[b];
  float acc = mb[o];
  const float* w = mw + (size_t)o * (2 * kH);
  for (int h = 0; h < kH; h++) acc += xg[b * kH + h] * invg * w[h];
  for (int h = 0; h < kH; h++) acc += xacc[b * kH + h] * invn * w[kH + h];
  out[idx] = acc;
}

extern "C" void kernel_launch(void* const* d_in, const int* in_sizes, int n_in,
                              void* d_out, int out_size, void* d_ws, size_t ws_size,
                              hipStream_t stream) {
  const float* node_emb = (const float*)d_in[0];
  const float* edge_emb = (const float*)d_in[1];
  const float* lin_w = (const float*)d_in[2];
  const float* lin_b = (const float*)d_in[3];
  const float* alpha_w = (const float*)d_in[4];
  const float* alpha_b = (const float*)d_in[5];
  const float* beta_w = (const float*)d_in[6];
  const float* beta_b = (const float*)d_in[7];
  const float* wr_w = (const float*)d_in[8];
  const float* wr_b = (const float*)d_in[9];
  const float* conv_w = (const float*)d_in[10];
  const float* conv_b = (const float*)d_in[11];
  const float* mlp_w = (const float*)d_in[12];
  const float* mlp_b = (const float*)d_in[13];
  const int* visit_node = (const int*)d_in[14];
  const int* ehr_nodes = (const int*)d_in[15];
  const int* cat_node_ids = (const int*)d_in[16];
  const int* cat_edge_ids = (const int*)d_in[17];
  const int* edge_index = (const int*)d_in[18];
  const int* batch = (const int*)d_in[19];

  char* ws = (char*)d_ws;
  float* ZP = (float*)(ws);                           // 25,165,824 (aliases XA; dead before l1)
  float* XA = (float*)(ws);                           // 51,200,000
  float* PN = (float*)(ws + 51200000);                // 768,512
  short* VNBF = (short*)(ws + 52100000);              // 1,540,096 (ends 53,640,096)
  short* AWH = (short*)(ws + 54000000);               // 27,144,192 (ends 81,144,192)
  int* CSN = (int*)(ws + 54000000);                   // 3,200,000 (aliases AWH; post-zmfma)
  int* CSRS2 = (int*)(ws + 57200000);                 // 3,200,000
  float* CS1C = (float*)(ws + 60400000);              // 3,200,000
  int* OFF2 = (int*)(ws + 63600000);                  // 400,004
  float* PQ2 = (float*)(ws + 81200000);               // 1,537,024
  float* PS = (float*)(ws + 82800000);                // 768,512
  float* ATTN = (float*)(ws + 102400000);             // 192,128
  float* BETA = (float*)(ws + 102592256);             // 3,840
  float* UC = (float*)(ws + 102596352);               // 1,032
  float* WREL = (float*)(ws + 102597632);             // 16,008
  int* OFF = (int*)(ws + 102613760);                  // 400,004
  int* CURSOR = (int*)(ws + 103014016);               // 400,000
  int* CURSOR2 = (int*)(ws + 103414016);              // 400,000 (contiguous w/ CURSOR)
  int* SPART = (int*)(ws + 103814016);                // 2,048
  int* SPART2 = (int*)(ws + 103816064);               // 2,048
  float* CS0 = (float*)(ws + 106616064);              // 3,200,000
  float* XG = (float*)(ws + 113016064);               // 8,192
  int* CNT = (int*)(ws + 113024256);                  // 64
  float* XNACC = (float*)(ws + 113024320);            // 8,192
  int* CNTE = (int*)(ws + 113032512);                 // 64

  pn_kernel<<<kNV, kH, 0, stream>>>(node_emb, lin_w, lin_b, conv_w, conv_b, PN, PQ2, PS);
  hipMemsetAsync(XG, 0, 16512, stream);
  xnode_kernel<<<dim3(kB, 12), kH, 0, stream>>>(ehr_nodes, PN, XNACC, CNTE);
  cnt_kernel<<<kNB, 256, 0, stream>>>(batch, CNT);
  uc_kernel<<<1, 256, 0, stream>>>(wr_w, wr_b, lin_w, lin_b, UC);
  wrel_kernel<<<(kL * kNE + 255) / 256, 256, 0, stream>>>(edge_emb, UC, WREL);
  beta_kernel<<<kL * kM, 64, 0, stream>>>(visit_node, beta_w, beta_b, BETA);
  vnbf_kernel<<<kMZ, 256, 0, stream>>>(visit_node, VNBF);
  awsplit_kernel<<<dim3(kKP, kL), 256, 0, stream>>>(alpha_w, AWH);
  zmfma_kernel<<<dim3(47, 2, kL * kKSZ), 256, 0, stream>>>(VNBF, AWH, ZP);
  zsm_kernel<<<(kL * kB * kNV + 255) / 256, 256, 0, stream>>>(ZP, BETA, ATTN);

  hipMemsetAsync(CURSOR, 0, 800000, stream);  // CURSOR + CURSOR2 (contiguous)
  hist_kernel<<<(kE + 255) / 256, 256, 0, stream>>>(edge_index, cat_node_ids, batch, ATTN,
                                                    CURSOR, CURSOR2);
  scan1_dual<<<kNB, 256, 0, stream>>>(CURSOR, CURSOR2, OFF, OFF2, SPART, SPART2);
  scan2_dual<<<1, 512, 0, stream>>>(SPART, SPART2);
  scan3_dual<<<kNB, 256, 0, stream>>>(OFF, SPART, CURSOR, OFF2, SPART2, CURSOR2);
  scatter_kernel<<<(kE + 255) / 256, 256, 0, stream>>>(edge_index, cat_node_ids, cat_edge_ids,
                                                       batch, ATTN, WREL, CURSOR, CSN, CS0,
                                                       CURSOR2, CSRS2, CS1C);

  // layer 1: output-space gather from PQ2/PS tables -> XA (clobbers dead ZP)
  l1_kernel<<<(kNT + 15) / 16, 512, 0, stream>>>(PQ2, PS, cat_node_ids, CSN, CS0, OFF,
                                                 CURSOR, XA);
  // layer 2: gather from XA via compacted positive CSR, fused pool -> XG
  gconv_kernel<1><<<(kNT + 63) / 64, 512, 0, stream>>>(XA, XA, CSRS2, CS1C, OFF2, CURSOR2,
                                                       nullptr, conv_w + (size_t)kH * kD,
                                                       conv_b + kH, nullptr, XG, batch);

  final_kernel<<<2, 256, 0, stream>>>(XG, CNT, XNACC, CNTE, mlp_w, mlp_b, (float*)d_out);
}